// Round 17
// baseline (1156.402 us; speedup 1.0000x reference)
//
#include <hip/hip_runtime.h>
#include <hip/hip_bf16.h>
#include <math.h>

// ---------------- problem constants ----------------
constexpr int C_  = 16;
constexpr int N_  = 10000;
constexpr int NC_ = 2000;
constexpr int E_  = 50000;
constexpr int D_  = 256;
constexpr int SZ_ = N_ * D_;          // per-config slab (elements)
constexpr float EPS_ = 1e-5f;

typedef unsigned short u16;
typedef __attribute__((ext_vector_type(8))) unsigned short us8v;
typedef __attribute__((ext_vector_type(4))) unsigned short us4v;
typedef __attribute__((ext_vector_type(8))) short s16x8;
typedef __attribute__((ext_vector_type(4))) float f32x4;

typedef __attribute__((address_space(3))) unsigned int lds_uint;
typedef const __attribute__((address_space(1))) unsigned int glb_uint;

__device__ __forceinline__ u16 f2bf(float f) {
    __hip_bfloat16 h = __float2bfloat16(f);   // hw v_cvt (RNE)
    return __builtin_bit_cast(u16, h);
}
__device__ __forceinline__ float bf2f(u16 h) {
    return __uint_as_float(((unsigned)h) << 16);
}
// fast gelu: erf via Abramowitz-Stegun 7.1.26 (|err|<=1.5e-7) + hw exp
__device__ __forceinline__ float gelu_f(float x) {
    float z = x * 0.70710678118654752f;
    float az = fabsf(z);
    float t = 1.f / fmaf(0.3275911f, az, 1.f);
    float p = t * (0.254829592f + t * (-0.284496736f + t * (1.421413741f +
              t * (-1.453152027f + t * 1.061405429f))));
    float e = p * __expf(-z * z);
    float erfv = (z >= 0.f) ? (1.f - e) : (e - 1.f);
    return 0.5f * x * (1.f + erfv);
}

// ---------------- tiny prep kernels ----------------

__global__ __launch_bounds__(256) void tbl_k(const float* __restrict__ embL,
                                             const float* __restrict__ W,
                                             float* __restrict__ T) {
    int b = blockIdx.x;            // 0..143
    int s = b >> 3, i = b & 7, d = threadIdx.x;
    float acc = 0.f;
#pragma unroll
    for (int k = 0; k < 4; ++k)
        acc = fmaf(embL[i * 4 + k], W[(134 + s * 4 + k) * 256 + d], acc);
    T[(s * 8 + i) * 256 + d] = acc;
}

// csum[d] = sum_s T[s][0][d]
__global__ __launch_bounds__(256) void csum_k(const float* __restrict__ T,
                                              float* __restrict__ cs) {
    int d = threadIdx.x;
    float a = 0.f;
#pragma unroll
    for (int s = 0; s < 18; ++s) a += T[(s * 8) * 256 + d];
    cs[d] = a;
}

__global__ __launch_bounds__(192) void feat_k(const float* __restrict__ xf,
                                              const int* __restrict__ xlay,
                                              const int* __restrict__ xop,
                                              const float* __restrict__ embL,
                                              const float* __restrict__ embO,
                                              float* __restrict__ f) {
    int n = blockIdx.x, j = threadIdx.x;
    if (j >= 176) return;
    float v;
    if (j < 134) v = xf[n * 134 + j];
    else if (j < 158) { int q = j - 134; int t = q >> 2, k = q & 3; v = embL[(xlay[n * 6 + t] + 2) * 4 + k]; }
    else if (j < 162) { int k = j - 158; v = embO[xop[n] * 4 + k]; }
    else v = 0.f;
    f[n * 176 + j] = v;
}

__global__ __launch_bounds__(256) void wpack_k(const float* __restrict__ W,
                                               float* __restrict__ Wp) {
    int j = blockIdx.x, d = threadIdx.x;
    float v = 0.f;
    if (j < 134) v = W[j * 256 + d];
    else if (j < 158) v = W[(206 + j - 134) * 256 + d];
    else if (j < 162) v = W[(230 + j - 158) * 256 + d];
    Wp[j * 256 + d] = v;
}

// pack channel-attn W1 [256][32] into MFMA fragment order
__global__ __launch_bounds__(256) void packw1_k(const float* __restrict__ W1,
                                                u16* __restrict__ dst) {
    int i = blockIdx.x * 256 + threadIdx.x;    // 0..8191
    int j = i & 7, lane = (i >> 3) & 63, half = (i >> 9) & 1, ks = (i >> 10) & 1, wid = (i >> 11) & 3;
    int k = wid * 64 + ks * 32 + ((lane >> 4) << 3) + j;
    int col = half * 16 + (lane & 15);
    dst[i] = f2bf(W1[k * 32 + col]);
}
// pack channel-attn W2 [32][256] into MFMA fragment order
__global__ __launch_bounds__(256) void packw2_k(const float* __restrict__ W2,
                                                u16* __restrict__ dst) {
    int i = blockIdx.x * 256 + threadIdx.x;    // 0..8191
    int j = i & 7, lane = (i >> 3) & 63, q = (i >> 9) & 3, wid = (i >> 11) & 3;
    int kq = lane >> 4, cl = lane & 15;
    dst[i] = f2bf(W2[(kq * 8 + j) * 256 + (wid * 4 + q) * 16 + cl]);
}

__global__ __launch_bounds__(256) void cfgpos_k(const int* __restrict__ ncid,
                                                int* __restrict__ cfgpos) {
    int i = blockIdx.x * 256 + threadIdx.x;
    if (i < NC_) cfgpos[ncid[i]] = i;
}

__global__ __launch_bounds__(256) void hist_k(const int* __restrict__ ei, int* __restrict__ cnt) {
    int e = blockIdx.x * 256 + threadIdx.x;
    if (e < E_) atomicAdd(&cnt[ei[E_ + e]], 1);
}

__global__ __launch_bounds__(1024) void scan_k(const int* __restrict__ cnt,
                                               int* __restrict__ off,
                                               int* __restrict__ cursor,
                                               float* __restrict__ invcnt) {
    __shared__ int s[1024];
    int t = threadIdx.x;
    int base = t * 10;
    int local[10];
    int part = 0;
#pragma unroll
    for (int k = 0; k < 10; ++k) {
        int idx = base + k;
        int v = (idx < N_) ? cnt[idx] : 0;
        local[k] = v; part += v;
    }
    s[t] = part;
    __syncthreads();
    for (int o = 1; o < 1024; o <<= 1) {
        int val = (t >= o) ? s[t - o] : 0;
        __syncthreads();
        s[t] += val;
        __syncthreads();
    }
    int pre = s[t] - part;
#pragma unroll
    for (int k = 0; k < 10; ++k) {
        int idx = base + k;
        if (idx < N_) {
            off[idx] = pre;
            cursor[idx] = pre;
            invcnt[idx] = 1.0f / (float)(local[k] > 1 ? local[k] : 1);
            pre += local[k];
        }
    }
    if (t == 1023) off[N_] = s[1023];
}

__global__ __launch_bounds__(256) void fill_k(const int* __restrict__ ei,
                                              int* __restrict__ cursor,
                                              int* __restrict__ csr) {
    int e = blockIdx.x * 256 + threadIdx.x;
    if (e < E_) {
        int t = ei[E_ + e];
        int p = atomicAdd(&cursor[t], 1);
        csr[p] = ei[e];
    }
}

// transpose lin2_W -> Wt2[j][k] bf16
__global__ __launch_bounds__(256) void wt2_k(const float* __restrict__ W,
                                             u16* __restrict__ Wt) {
    int j = blockIdx.x, k = threadIdx.x;
    Wt[j * 256 + k] = f2bf(W[k * 256 + j]);
}

// fold instance-norm into sage weights (per config); stats computed inline
__global__ __launch_bounds__(256) void foldw_k(const float* __restrict__ Wl,
                                               const float* __restrict__ Wr,
                                               const float* __restrict__ bl,
                                               const float* __restrict__ nssum,
                                               const float* __restrict__ nssq,
                                               u16* __restrict__ Wt,
                                               float* __restrict__ biasF) {
    __shared__ float red[256];
    int c = blockIdx.y, j = blockIdx.x, k = threadIdx.x;
    float m = nssum[c * 256 + k] * (1.0f / (float)N_);
    float v = nssq[c * 256 + k] * (1.0f / (float)N_) - m * m;
    float rsv = rsqrtf(v + EPS_);
    float muv = m;
    float fl = rsv * Wl[k * 256 + j];
    float fr = rsv * Wr[k * 256 + j];
    size_t wb = ((size_t)c * 256 + j) * 512;
    Wt[wb + k] = f2bf(fl);
    Wt[wb + 256 + k] = f2bf(fr);
    red[k] = muv * (fl + fr);
    __syncthreads();
    for (int s = 128; s > 0; s >>= 1) {
        if (k < s) red[k] += red[k + s];
        __syncthreads();
    }
    if (k == 0) biasF[c * 256 + j] = bl[j] - red[0];
}

// ---------------- lin1 (configured nodes) ----------------
__global__ __launch_bounds__(256) void lin1_cfg_k(const float* __restrict__ base,
                                                  const float* __restrict__ T,
                                                  const int* __restrict__ ncid,
                                                  const int* __restrict__ xcfg,
                                                  u16* __restrict__ H,
                                                  float* __restrict__ ssum,
                                                  float* __restrict__ ssq) {
    __shared__ int idxs[16][18];   // premultiplied by 256
    __shared__ int nid[16];
    const int c = blockIdx.z, j0 = blockIdx.x * 16, tid = threadIdx.x;
    if (tid < 16) nid[tid] = ncid[j0 + tid];
    for (int t = tid; t < 288; t += 256) {
        int row = t / 18, s = t - row * 18;
        idxs[row][s] = (xcfg[((size_t)c * NC_ + j0 + row) * 18 + s] + 2) * 256;
    }
    __syncthreads();
    const int d = tid;
    float psum = 0.f, psq = 0.f;
    for (int g = 0; g < 16; g += 4) {
        float acc[4];
#pragma unroll
        for (int gg = 0; gg < 4; ++gg) acc[gg] = base[(size_t)nid[g + gg] * 256 + d];
#pragma unroll
        for (int s = 0; s < 18; ++s) {
            const float* Ts = &T[s * 2048 + d];
#pragma unroll
            for (int gg = 0; gg < 4; ++gg)
                acc[gg] += Ts[idxs[g + gg][s]];
        }
#pragma unroll
        for (int gg = 0; gg < 4; ++gg) {
            H[((size_t)c * N_ + nid[g + gg]) * 256 + d] = f2bf(acc[gg]);
            psum += acc[gg]; psq += acc[gg] * acc[gg];
        }
    }
    atomicAdd(&ssum[c * 256 + d], psum);
    atomicAdd(&ssq[c * 256 + d], psq);
}

// ---------------- lin1 (unconfigured nodes) ----------------
__global__ __launch_bounds__(256) void lin1_unc_k(const float* __restrict__ base,
                                                  const float* __restrict__ csum,
                                                  const int* __restrict__ cfgpos,
                                                  int nc,
                                                  u16* __restrict__ H,
                                                  float* __restrict__ ssum,
                                                  float* __restrict__ ssq) {
    __shared__ float red[2048];
    const int n0 = blockIdx.x * 16, tid = threadIdx.x;
    float ps[8] = {0, 0, 0, 0, 0, 0, 0, 0}, pq[8] = {0, 0, 0, 0, 0, 0, 0, 0};
#pragma unroll
    for (int it = 0; it < 2; ++it) {
        const int flat = tid + it * 256;
        const int row = flat >> 5, cb = (flat & 31) * 8;
        const int n = n0 + row;
        if (cfgpos[n] >= 0) continue;
        us8v b;
#pragma unroll
        for (int j = 0; j < 8; ++j) {
            float v = base[(size_t)n * 256 + cb + j] + csum[cb + j];
            b[j] = f2bf(v);
            ps[j] += v; pq[j] += v * v;
        }
        for (int c = 0; c < nc; ++c)
            *(us8v*)&H[((size_t)c * N_ + n) * 256 + cb] = b;
    }
#pragma unroll
    for (int j = 0; j < 8; ++j)
        red[((tid >> 5) * 32 + (tid & 31)) * 8 + j] = ps[j];
    __syncthreads();
    {
        const int cb2 = tid >> 3, j2 = tid & 7;
        float s = 0.f;
#pragma unroll
        for (int r8 = 0; r8 < 8; ++r8) s += red[(r8 * 32 + cb2) * 8 + j2];
        for (int c = 0; c < nc; ++c) atomicAdd(&ssum[c * 256 + tid], s);
    }
    __syncthreads();
#pragma unroll
    for (int j = 0; j < 8; ++j)
        red[((tid >> 5) * 32 + (tid & 31)) * 8 + j] = pq[j];
    __syncthreads();
    {
        const int cb2 = tid >> 3, j2 = tid & 7;
        float s = 0.f;
#pragma unroll
        for (int r8 = 0; r8 < 8; ++r8) s += red[(r8 * 32 + cb2) * 8 + j2];
        for (int c = 0; c < nc; ++c) atomicAdd(&ssq[c * 256 + tid], s);
    }
}

// ---------------- CSR gather-mean: vector index load + shfl broadcast ----------------
// deg-0 rows write mu computed inline from ssum
__global__ __launch_bounds__(256) void agg_k(const u16* __restrict__ H,
                                             const int* __restrict__ off,
                                             const int* __restrict__ csr,
                                             const float* __restrict__ invcnt,
                                             const float* __restrict__ nssum,
                                             u16* __restrict__ Agg) {
    int wave = threadIdx.x >> 6, lane = threadIdx.x & 63;
    int pair = blockIdx.x * 4 + wave;
    int c = pair / N_, t = pair - c * N_;
    int d4 = lane * 4;
    int o0 = off[t], o1 = off[t + 1];
    int deg = o1 - o0;
    us4v o;
    if (deg > 0) {
        int myidx = (lane < deg) ? csr[o0 + lane] : 0;
        const u16* Hc = H + (size_t)c * SZ_ + d4;
        float ax = 0.f, ay = 0.f, az = 0.f, aw = 0.f;
        int lim = deg < 64 ? deg : 64;
        int i = 0;
        for (; i + 4 <= lim; i += 4) {
            int s0 = __shfl(myidx, i), s1 = __shfl(myidx, i + 1);
            int s2 = __shfl(myidx, i + 2), s3 = __shfl(myidx, i + 3);
            us4v h0 = *(const us4v*)&Hc[(size_t)s0 * 256];
            us4v h1 = *(const us4v*)&Hc[(size_t)s1 * 256];
            us4v h2 = *(const us4v*)&Hc[(size_t)s2 * 256];
            us4v h3 = *(const us4v*)&Hc[(size_t)s3 * 256];
            ax += (bf2f(h0.x) + bf2f(h1.x)) + (bf2f(h2.x) + bf2f(h3.x));
            ay += (bf2f(h0.y) + bf2f(h1.y)) + (bf2f(h2.y) + bf2f(h3.y));
            az += (bf2f(h0.z) + bf2f(h1.z)) + (bf2f(h2.z) + bf2f(h3.z));
            aw += (bf2f(h0.w) + bf2f(h1.w)) + (bf2f(h2.w) + bf2f(h3.w));
        }
        for (; i < lim; ++i) {
            int s = __shfl(myidx, i);
            us4v h = *(const us4v*)&Hc[(size_t)s * 256];
            ax += bf2f(h.x); ay += bf2f(h.y); az += bf2f(h.z); aw += bf2f(h.w);
        }
        for (int j = o0 + 64; j < o1; ++j) {     // rare: degree > 64
            int s = csr[j];
            us4v h = *(const us4v*)&Hc[(size_t)s * 256];
            ax += bf2f(h.x); ay += bf2f(h.y); az += bf2f(h.z); aw += bf2f(h.w);
        }
        float inv = invcnt[t];
        o.x = f2bf(ax * inv); o.y = f2bf(ay * inv);
        o.z = f2bf(az * inv); o.w = f2bf(aw * inv);
    } else {
        const float invN = 1.0f / (float)N_;
        o.x = f2bf(nssum[c * 256 + d4 + 0] * invN);
        o.y = f2bf(nssum[c * 256 + d4 + 1] * invN);
        o.z = f2bf(nssum[c * 256 + d4 + 2] * invN);
        o.w = f2bf(nssum[c * 256 + d4 + 3] * invN);
    }
    *(us4v*)&Agg[((size_t)c * N_ + t) * 256 + d4] = o;
}

// ---------------- bf16 MFMA GEMM (128x128 tile, 2-phase dbuf): Y = [A1|A2] @ Wt^T + bias ----------------
template <int STATS>
__global__ __launch_bounds__(256) void mgemm_k(
    const u16* __restrict__ A1, size_t sA1,
    const u16* __restrict__ A2, size_t sA2,
    const u16* __restrict__ Wt, size_t sW, int K1, int Ktot,
    const float* __restrict__ bias, size_t sBias,
    u16* __restrict__ Y, size_t sY, int Mrows,
    float* __restrict__ ssum, float* __restrict__ ssq)
{
    __shared__ __align__(16) char SM[65536];   // 2 x (A 16KB + B 16KB)
    const int tid = threadIdx.x;
    const int lane = tid & 63, wid = tid >> 6;
    const int wr = wid >> 1, wc = wid & 1;

    // XCD-aware bijective remap of the flattened block id
    const int gx = gridDim.x, gy = gridDim.y;
    int nwg = gx * gy * gridDim.z;
    int orig = blockIdx.x + gx * (blockIdx.y + gy * blockIdx.z);
    int q = nwg >> 3, r = nwg & 7;
    int xcd = orig & 7, idx = orig >> 3;
    int swz = (xcd < r ? xcd * (q + 1) : r * (q + 1) + (xcd - r) * q) + idx;
    const int bx = swz % gx;
    const int tmp = swz / gx;
    const int by = tmp % gy;
    const int c  = tmp / gy;

    const int rowbase = by * 128, colbase = bx * 128;

    const u16* A1p = A1 + (size_t)c * sA1;
    const u16* A2p = A2 ? (A2 + (size_t)c * sA2) : nullptr;
    const u16* Wp  = Wt + (size_t)c * sW;

    f32x4 acc[4][4];
#pragma unroll
    for (int i = 0; i < 4; ++i)
#pragma unroll
        for (int j = 0; j < 4; ++j) acc[i][j] = (f32x4)0.f;

    auto stage = [&](int buf, int k0) {
        const u16* asrc; int ak;
        if (k0 < K1) { asrc = A1p; ak = k0; } else { asrc = A2p; ak = k0 - K1; }
        u16* Ab = (u16*)(SM + buf * 32768);
        u16* Bb = (u16*)(SM + buf * 32768 + 16384);
#pragma unroll
        for (int jj = 0; jj < 4; ++jj) {
            const int u = tid + jj * 256;
            const int row = u >> 3, chunk = u & 7;
            const int sc2 = chunk ^ (row & 7);
            int garow = rowbase + row;
            if (garow >= Mrows) garow = Mrows - 1;             // clamp: values unused
            __builtin_amdgcn_global_load_lds(
                (glb_uint*)(asrc + (size_t)garow * 256 + ak + sc2 * 8),
                (lds_uint*)(Ab + u * 8), 16, 0, 0);
            __builtin_amdgcn_global_load_lds(
                (glb_uint*)(Wp + (size_t)(colbase + row) * Ktot + k0 + sc2 * 8),
                (lds_uint*)(Bb + u * 8), 16, 0, 0);
        }
    };

    const int nsteps = Ktot >> 6;
    stage(0, 0);
    __syncthreads();                 // drain prologue (implicit vmcnt(0))
    int cur = 0;
    for (int t = 0; t < nsteps; ++t) {
        if (t + 1 < nsteps) stage(cur ^ 1, (t + 1) * 64);   // overlap with MFMA
        const u16* Asm = (const u16*)(SM + cur * 32768);
        const u16* Bsm = (const u16*)(SM + cur * 32768 + 16384);
#pragma unroll
        for (int ks = 0; ks < 2; ++ks) {
            s16x8 aF[4], bF[4];
            const int kk = ks * 32 + ((lane >> 4) << 3);
#pragma unroll
            for (int f = 0; f < 4; ++f) {
                int ar = wr * 64 + f * 16 + (lane & 15);
                aF[f] = *(const s16x8*)&Asm[(ar * 64 + kk) ^ ((ar & 7) << 3)];
                int br = wc * 64 + f * 16 + (lane & 15);
                bF[f] = *(const s16x8*)&Bsm[(br * 64 + kk) ^ ((br & 7) << 3)];
            }
#pragma unroll
            for (int fr = 0; fr < 4; ++fr)
#pragma unroll
                for (int fc = 0; fc < 4; ++fc)
                    acc[fr][fc] = __builtin_amdgcn_mfma_f32_16x16x32_bf16(
                        aF[fr], bF[fc], acc[fr][fc], 0, 0, 0);
        }
        __syncthreads();             // next buf staged, cur reads done
        cur ^= 1;
    }

    float bcol[4];
#pragma unroll
    for (int fc = 0; fc < 4; ++fc)
        bcol[fc] = bias[(size_t)c * sBias + colbase + wc * 64 + fc * 16 + (lane & 15)];
    u16* Yp = Y + (size_t)c * sY;
    float ps[4] = {0, 0, 0, 0}, pq[4] = {0, 0, 0, 0};
#pragma unroll
    for (int fr = 0; fr < 4; ++fr) {
#pragma unroll
        for (int i = 0; i < 4; ++i) {
            int grow = rowbase + wr * 64 + fr * 16 + ((lane >> 4) << 2) + i;
            if (grow < Mrows) {
                size_t rb = (size_t)grow * 256 + colbase + wc * 64 + (lane & 15);
#pragma unroll
                for (int fc = 0; fc < 4; ++fc) {
                    float v = acc[fr][fc][i] + bcol[fc];
                    Yp[rb + fc * 16] = f2bf(v);
                    if (STATS) { ps[fc] += v; pq[fc] += v * v; }
                }
            }
        }
    }
    if (STATS) {
#pragma unroll
        for (int fc = 0; fc < 4; ++fc) {
            float s = ps[fc], q2 = pq[fc];
            s += __shfl_xor(s, 16); s += __shfl_xor(s, 32);
            q2 += __shfl_xor(q2, 16); q2 += __shfl_xor(q2, 32);
            if (lane < 16) {
                int col = colbase + wc * 64 + fc * 16 + lane;
                atomicAdd(&ssum[c * 256 + col], s);
                atomicAdd(&ssq[c * 256 + col], q2);
            }
        }
    }
}

// ---------------- FUSED sage: Y = gelu(chattn([Agg|H] @ Wfold^T + biasF) + H) ----------------
// 64 rows x 256 cols tile, K=512 in 16 steps of 32, 512 threads / 8 waves.
// Double-buffered staging, 20KB/buf -> LDS 40KB -> 4 blocks/CU = 32 waves/CU.
// Chunk swizzle uses ((r>>1)&3): with 16-bank row stride this spans all 8
// chunk-slots over any 16 consecutive rows -> 2-way (free) ds_read_b128.
template <int SMODE>   // 1: sum+sumsq, 2: sum only
__global__ __launch_bounds__(512) void msage_k(
    const u16* __restrict__ A1,                 // Agg slabs
    const u16* __restrict__ A2,                 // H slabs (also residual, in-place out)
    const u16* __restrict__ Wt, size_t sW,      // folded weights [256][512] per config
    const float* __restrict__ biasF,            // [nc][256]
    const u16* __restrict__ W1p, const float* __restrict__ b1,
    const u16* __restrict__ W2p, const float* __restrict__ b2,
    u16* __restrict__ Yout, int Mrows,
    float* __restrict__ ssum, float* __restrict__ ssq)
{
    __shared__ __align__(16) char SM[40960];
    // buf b: A at b*20480 (4096 B, 64x32), B at b*20480+4096 (16384 B, 256x32)
    u16*   xbf = (u16*)SM;                      // 64x264  (epilogue, aliases bufs)
    u16*   tbf = (u16*)(SM + 33792);            // 64x40   (epilogue)
    float* red = (float*)SM;                    // stats reduce (aliases dead xbf)

    const int tid = threadIdx.x;
    const int lane = tid & 63, w = tid >> 6;     // wave 0..7 (col-32 slice)
    const int cl = lane & 15, kq = lane >> 4;

    // XCD-aware bijective remap over (by, c)
    int nwg = gridDim.x * gridDim.y;
    int orig = blockIdx.x + gridDim.x * blockIdx.y;
    int q = nwg >> 3, r = nwg & 7;
    int xcd = orig & 7, idx = orig >> 3;
    int swz = (xcd < r ? xcd * (q + 1) : r * (q + 1) + (xcd - r) * q) + idx;
    const int by = swz % gridDim.x;
    const int c  = swz / gridDim.x;
    const int rowbase = by * 64;

    const u16* A1p = A1 + (size_t)c * SZ_;
    const u16* A2p = A2 + (size_t)c * SZ_;
    const u16* Wp  = Wt + (size_t)c * sW;

    f32x4 acc[4][2];
#pragma unroll
    for (int i = 0; i < 4; ++i)
#pragma unroll
        for (int j = 0; j < 2; ++j) acc[i][j] = (f32x4)0.f;

    // K-step = 32: A tile 64x32 (256 16B units), B tile 256x32 (1024 units)
    auto stage = [&](int buf, int k0) {
        const u16* asrc = (k0 < 256) ? A1p : A2p;
        const int ak = (k0 < 256) ? k0 : (k0 - 256);
        u16* Ab = (u16*)(SM + buf * 20480);
        u16* Bb = (u16*)(SM + buf * 20480 + 4096);
        // A: 256 units, threads 0..255 (waves 0..3), 1/thread
        if (tid < 256) {
            const int row = tid >> 2, chunk = tid & 3;
            const int sc2 = chunk ^ ((row >> 1) & 3);
            int garow = rowbase + row;
            if (garow >= Mrows) garow = Mrows - 1;
            __builtin_amdgcn_global_load_lds(
                (glb_uint*)(asrc + (size_t)garow * 256 + ak + sc2 * 8),
                (lds_uint*)(Ab + tid * 8), 16, 0, 0);
        }
        // B: 1024 units, 2/thread
#pragma unroll
        for (int jj = 0; jj < 2; ++jj) {
            const int u = tid + jj * 512;
            const int wcol = u >> 2, chunk = u & 3;
            const int sc2 = chunk ^ ((wcol >> 1) & 3);
            __builtin_amdgcn_global_load_lds(
                (glb_uint*)(Wp + (size_t)wcol * 512 + k0 + sc2 * 8),
                (lds_uint*)(Bb + u * 8), 16, 0, 0);
        }
    };

    // ---- 2-phase pipelined K loop: Ktot = 512, 16 steps of 32 ----
    stage(0, 0);
    __syncthreads();                 // drain prologue stage (implicit vmcnt(0))
    int cur = 0;
    for (int t = 0; t < 16; ++t) {
        if (t < 15) stage(cur ^ 1, (t + 1) * 32);   // overlap with MFMA below
        const u16* Asm = (const u16*)(SM + cur * 20480);
        const u16* Bsm = (const u16*)(SM + cur * 20480 + 4096);
        {
            s16x8 aF[4], bF[2];
            const int kk = kq * 8;
#pragma unroll
            for (int f = 0; f < 4; ++f) {
                const int ar = f * 16 + cl;
                aF[f] = *(const s16x8*)&Asm[(ar * 32 + kk) ^ (((ar >> 1) & 3) << 3)];
            }
#pragma unroll
            for (int fc = 0; fc < 2; ++fc) {
                const int bc = w * 32 + fc * 16 + cl;
                bF[fc] = *(const s16x8*)&Bsm[(bc * 32 + kk) ^ (((bc >> 1) & 3) << 3)];
            }
#pragma unroll
            for (int fr = 0; fr < 4; ++fr)
#pragma unroll
                for (int fc = 0; fc < 2; ++fc)
                    acc[fr][fc] = __builtin_amdgcn_mfma_f32_16x16x32_bf16(
                        aF[fr], bF[fc], acc[fr][fc], 0, 0, 0);
        }
        __syncthreads();             // drains vmcnt(0): next buf ready, cur reads done
        cur ^= 1;
    }

    float bcol[2];
#pragma unroll
    for (int fc = 0; fc < 2; ++fc)
        bcol[fc] = biasF[c * 256 + w * 32 + fc * 16 + cl];

    // ---- attention epilogue ----
#pragma unroll
    for (int fr = 0; fr < 4; ++fr)
#pragma unroll
        for (int i = 0; i < 4; ++i) {
            const int rloc = fr * 16 + kq * 4 + i;
#pragma unroll
            for (int fc = 0; fc < 2; ++fc)
                xbf[rloc * 264 + w * 32 + fc * 16 + cl] =
                    f2bf(acc[fr][fc][i] + bcol[fc]);
        }
    __syncthreads();
    // t = relu(x@W1 + b1): wave = (rb = w>>1 row-block, ch = w&1 col-half), K=256
    {
        const int rb = w >> 1, ch = w & 1;
        f32x4 at = (f32x4)0.f;
#pragma unroll
        for (int s = 0; s < 8; ++s) {
            s16x8 aF = *(const s16x8*)&xbf[(rb * 16 + cl) * 264 + s * 32 + kq * 8];
            s16x8 bF = *(const s16x8*)&W1p[((s * 2 + ch) * 64 + lane) * 8];
            at = __builtin_amdgcn_mfma_f32_16x16x32_bf16(aF, bF, at, 0, 0, 0);
        }
        const float b1v = b1[ch * 16 + cl];
#pragma unroll
        for (int i = 0; i < 4; ++i)
            tbf[(rb * 16 + kq * 4 + i) * 40 + ch * 16 + cl] =
                f2bf(fmaxf(at[i] + b1v, 0.f));
    }
    __syncthreads();
    // y' = sigmoid(t@W2 + b2) * x  -> back into xbf (wave = col-32 slice, 2 col frags)
    {
        s16x8 aF[4];
#pragma unroll
        for (int rg = 0; rg < 4; ++rg)
            aF[rg] = *(const s16x8*)&tbf[(rg * 16 + cl) * 40 + kq * 8];
#pragma unroll
        for (int q2 = 0; q2 < 2; ++q2) {
            const int cf = w * 2 + q2;            // 0..15
            const int colb = cf * 16;
            s16x8 bF = *(const s16x8*)&W2p[(cf * 64 + lane) * 8];
            const float b2v = b2[colb + cl];
#pragma unroll
            for (int rg = 0; rg < 4; ++rg) {
                f32x4 a2 = __builtin_amdgcn_mfma_f32_16x16x32_bf16(
                    aF[rg], bF, (f32x4)0.f, 0, 0, 0);
#pragma unroll
                for (int i = 0; i < 4; ++i) {
                    const int ea = (rg * 16 + kq * 4 + i) * 264 + colb + cl;
                    float s = a2[i] + b2v;
                    float sig = 1.f / (1.f + __expf(-s));
                    xbf[ea] = f2bf(sig * bf2f(xbf[ea]));
                }
            }
        }
    }
    __syncthreads();
    // gelu(y' + res), coalesced store + stats (32 elements/thread)
    float ps[8] = {0, 0, 0, 0, 0, 0, 0, 0}, pq[8] = {0, 0, 0, 0, 0, 0, 0, 0};
#pragma unroll
    for (int it = 0; it < 4; ++it) {
        const int e = tid + it * 512;
        const int row = e >> 5, cb = (e & 31) * 8;
        const int grow = rowbase + row;
        if (grow < Mrows) {
            us8v xv = *(const us8v*)&xbf[row * 264 + cb];
            us8v rv = *(const us8v*)&Yout[((size_t)c * N_ + grow) * 256 + cb];
            us8v ov;
#pragma unroll
            for (int j = 0; j < 8; ++j) {
                float v = gelu_f(bf2f(xv[j]) + bf2f(rv[j]));
                ov[j] = f2bf(v);
                ps[j] += v;
                if (SMODE == 1) pq[j] += v * v;
            }
            *(us8v*)&Yout[((size_t)c * N_ + grow) * 256 + cb] = ov;
        }
    }
    __syncthreads();                 // xbf dead -> red may alias it
#pragma unroll
    for (int j = 0; j < 8; ++j)
        red[((tid >> 5) * 32 + (tid & 31)) * 8 + j] = ps[j];
    __syncthreads();
    if (tid < 256) {
        const int cb2 = tid >> 3, j2 = tid & 7;
        float s = 0.f;
#pragma unroll
        for (int r16 = 0; r16 < 16; ++r16) s += red[(r16 * 32 + cb2) * 8 + j2];
        atomicAdd(&ssum[c * 256 + cb2 * 8 + j2], s);
    }
    if (SMODE == 1) {
        __syncthreads();
#pragma unroll
        for (int j = 0; j < 8; ++j)
            red[((tid >> 5) * 32 + (tid & 31)) * 8 + j] = pq[j];
        __syncthreads();
        if (tid < 256) {
            const int cb2 = tid >> 3, j2 = tid & 7;
            float s = 0.f;
#pragma unroll
            for (int r16 = 0; r16 < 16; ++r16) s += red[(r16 * 32 + cb2) * 8 + j2];
            atomicAdd(&ssq[c * 256 + cb2 * 8 + j2], s);
        }
    }
}

// ---------------- fp32 tiled GEMM (one-time base GEMM) ----------------
__global__ __launch_bounds__(256) void gemm_k(const float* __restrict__ A1, int lda1,
                                              const float* __restrict__ W1, int K1,
                                              const float* __restrict__ bias,
                                              float* __restrict__ Y, int Mrows) {
    __shared__ float As[16][132];
    __shared__ float Bs[16][132];
    float acc[8][8];
#pragma unroll
    for (int i = 0; i < 8; ++i)
#pragma unroll
        for (int j = 0; j < 8; ++j) acc[i][j] = 0.f;

    const int tid = threadIdx.x;
    const int tr = tid >> 4, tc = tid & 15;
    const int rowbase = blockIdx.y * 128, colbase = blockIdx.x * 128;

    for (int k0 = 0; k0 < K1; k0 += 16) {
#pragma unroll
        for (int ii = 0; ii < 2; ++ii) {
            int i = tid + ii * 256;
            int rr = i >> 2, qq = i & 3;
            int grow = rowbase + rr;
            float4 vv = make_float4(0.f, 0.f, 0.f, 0.f);
            if (grow < Mrows) vv = *(const float4*)&A1[(size_t)grow * lda1 + k0 + qq * 4];
            As[qq * 4 + 0][rr] = vv.x;
            As[qq * 4 + 1][rr] = vv.y;
            As[qq * 4 + 2][rr] = vv.z;
            As[qq * 4 + 3][rr] = vv.w;
        }
#pragma unroll
        for (int ii = 0; ii < 2; ++ii) {
            int i = tid + ii * 256;
            int rr = i >> 5, qq = i & 31;
            float4 vv = *(const float4*)&W1[(size_t)(k0 + rr) * 256 + colbase + qq * 4];
            *(float4*)&Bs[rr][qq * 4] = vv;
        }
        __syncthreads();
#pragma unroll
        for (int kk = 0; kk < 16; ++kk) {
            float a[8], b[8];
            *(float4*)&a[0] = *(const float4*)&As[kk][tr * 4];
            *(float4*)&a[4] = *(const float4*)&As[kk][64 + tr * 4];
            *(float4*)&b[0] = *(const float4*)&Bs[kk][tc * 4];
            *(float4*)&b[4] = *(const float4*)&Bs[kk][64 + tc * 4];
#pragma unroll
            for (int i = 0; i < 8; ++i)
#pragma unroll
                for (int j = 0; j < 8; ++j)
                    acc[i][j] = fmaf(a[i], b[j], acc[i][j]);
        }
        __syncthreads();
    }

    float4 blo = *(const float4*)&bias[colbase + tc * 4];
    float4 bhi = *(const float4*)&bias[colbase + 64 + tc * 4];
    float bb[8] = {blo.x, blo.y, blo.z, blo.w, bhi.x, bhi.y, bhi.z, bhi.w};
#pragma unroll
    for (int i = 0; i < 8; ++i)
#pragma unroll
        for (int j = 0; j < 8; ++j) acc[i][j] += bb[j];

#pragma unroll
    for (int i = 0; i < 8; ++i) {
        int lrow = (i < 4) ? (tr * 4 + i) : (64 + tr * 4 + (i - 4));
        int grow = rowbase + lrow;
        if (grow < Mrows) {
            *(float4*)&Y[(size_t)grow * 256 + colbase + tc * 4] =
                make_float4(acc[i][0], acc[i][1], acc[i][2], acc[i][3]);
            *(float4*)&Y[(size_t)grow * 256 + colbase + 64 + tc * 4] =
                make_float4(acc[i][4], acc[i][5], acc[i][6], acc[i][7]);
        }
    }
}

// ---------------- per-row epilogue with MFMA channel-attention (512 thr, 8 waves) ----------------
// norm stats computed inline from nssum/nssq (finstat removed)
template <int NORM, int RES, int SMODE>
__global__ __launch_bounds__(512) void apply_k(const u16* __restrict__ Yin,
                                               u16* __restrict__ Hout,
                                               const u16* __restrict__ Hsc,
                                               const u16* __restrict__ W1p,
                                               const float* __restrict__ b1,
                                               const u16* __restrict__ W2p,
                                               const float* __restrict__ b2,
                                               const float* __restrict__ nssum,
                                               const float* __restrict__ nssq,
                                               float* __restrict__ ssum,
                                               float* __restrict__ ssq) {
    __shared__ u16 vbf[16 * 264];
    __shared__ u16 scs[(RES ? 16 : 1) * 264];
    __shared__ float tpart[8 * 528];
    __shared__ u16 tbf[16 * 40];
    __shared__ float srs[NORM ? 256 : 1], smrs[NORM ? 256 : 1];
    const int c = blockIdx.z, n0 = blockIdx.x * 16, tid = threadIdx.x;
    const int lane = tid & 63, wid = tid >> 6;   // wid 0..7
    const size_t rowbase = ((size_t)c * N_ + n0) * 256;

    if (NORM && tid < 256) {
        float m = nssum[c * 256 + tid] * (1.0f / (float)N_);
        float v = nssq[c * 256 + tid] * (1.0f / (float)N_) - m * m;
        float r = rsqrtf(v + EPS_);
        srs[tid] = r;
        smrs[tid] = m * r;
    }
    {
        const int row = tid >> 5, cb = (tid & 31) * 8;
        us8v x = *(const us8v*)&Yin[rowbase + row * 256 + cb];
        us8v r;
        if (RES) r = *(const us8v*)&Hsc[rowbase + row * 256 + cb];
        if (NORM) {
            __syncthreads();
            us8v y;
#pragma unroll
            for (int j = 0; j < 8; ++j)
                y[j] = f2bf(fmaf(bf2f(x[j]), srs[cb + j], -smrs[cb + j]));
            *(us8v*)&vbf[row * 264 + cb] = y;
        } else {
            *(us8v*)&vbf[row * 264 + cb] = x;
        }
        if (RES) *(us8v*)&scs[row * 264 + cb] = r;
    }
    __syncthreads();

    {
        const int arow = lane & 15, kq = lane >> 4;
        const int k = wid * 32 + kq * 8;
        s16x8 aF = *(const s16x8*)&vbf[arow * 264 + k];
        s16x8 bF0 = *(const s16x8*)&W1p[((wid * 2 + 0) * 64 + lane) * 8];
        s16x8 bF1 = *(const s16x8*)&W1p[((wid * 2 + 1) * 64 + lane) * 8];
        f32x4 at0 = __builtin_amdgcn_mfma_f32_16x16x32_bf16(aF, bF0, (f32x4)0.f, 0, 0, 0);
        f32x4 at1 = __builtin_amdgcn_mfma_f32_16x16x32_bf16(aF, bF1, (f32x4)0.f, 0, 0, 0);
#pragma unroll
        for (int i = 0; i < 4; ++i) {
            tpart[wid * 528 + (kq * 4 + i) * 33 + (lane & 15)] = at0[i];
            tpart[wid * 528 + (kq * 4 + i) * 33 + 16 + (lane & 15)] = at1[i];
        }
    }
    __syncthreads();

    {
        const int nr = tid >> 5, col = tid & 31;
        float s = b1[col];
#pragma unroll
        for (int w8 = 0; w8 < 8; ++w8)
            s += tpart[w8 * 528 + nr * 33 + col];
        tbf[nr * 40 + col] = f2bf(fmaxf(s, 0.f));
    }
    __syncthreads();

    {
        const int cl = lane & 15, kq = lane >> 4;
        s16x8 aF = *(const s16x8*)&tbf[cl * 40 + kq * 8];
        float ps[2] = {0, 0}, pq[2] = {0, 0};
#pragma unroll
        for (int q = 0; q < 2; ++q) {
            const int colb = (wid * 2 + q) * 16;
            s16x8 bF = *(const s16x8*)&W2p[((wid * 2 + q) * 64 + lane) * 8];
            f32x4 acc = __builtin_amdgcn_mfma_f32_16x16x32_bf16(aF, bF, (f32x4)0.f, 0, 0, 0);
            const float b2v = b2[colb + cl];
#pragma unroll
            for (int i = 0; i < 4; ++i) {
                const int row = kq * 4 + i;
                const int ea = row * 264 + colb + cl;
                float s = acc[i] + b2v;
                float sig = 1.0f / (1.0f + __expf(-s));
                float val = sig * bf2f(vbf[ea]);
                if (RES) val += bf2f(scs[ea]);
                val = gelu_f(val);
                vbf[ea] = f2bf(val);
                if (SMODE) { ps[q] += val; if (SMODE == 1) pq[q] += val * val; }
            }
        }
        if (SMODE) {
#pragma unroll
            for (int q = 0; q < 2; ++q) {
                float s = ps[q];
                s += __shfl_xor(s, 16); s += __shfl_xor(s, 32);
                if (SMODE == 1) {
                    float q2 = pq[q];
                    q2 += __shfl_xor(q2, 16); q2 += __shfl_xor(q2, 32);
                    if (lane < 16) atomicAdd(&ssq[c * 256 + (wid * 2 + q) * 16 + lane], q2);
                }
                if (lane < 16) atomicAdd(&ssum[c * 256 + (wid * 2 + q) * 16 + lane], s);
            }
        }
    }
    __syncthreads();

    {
        const int row = tid >> 5, cb = (tid & 31) * 8;
        us8v h = *(const us8v*)&vbf[row * 264 + cb];
        *(us8v*)&Hout[rowbase + row * 256 + cb] = h;
    }
}

// ---------------- classifier ----------------
__global__ __launch_bounds__(256) void cls_k(const float* __restrict__ pooled_sum,
                                             const float* __restrict__ clsW,
                                             const float* __restrict__ clsb,
                                             float* __restrict__ out) {
    __shared__ float red[256];
    int c = blockIdx.x, d = threadIdx.x;
    red[d] = pooled_sum[c * 256 + d] * (1.0f / (float)N_) * clsW[d];
    __syncthreads();
    for (int s = 128; s > 0; s >>= 1) {
        if (d < s) red[d] += red[d + s];
        __syncthreads();
    }
    if (d == 0) out[c] = red[0] + clsb[0];
}

// ---------------- host launch ----------------
static inline size_t alup(size_t x) { return (x + 255) & ~(size_t)255; }

extern "C" void kernel_launch(void* const* d_in, const int* in_sizes, int n_in,
                              void* d_out, int out_size, void* d_ws, size_t ws_size,
                              hipStream_t stream) {
    const int*   xcfg   = (const int*)d_in[0];
    const float* xfeat  = (const float*)d_in[1];
    const int*   xlay   = (const int*)d_in[2];
    const int*   xop    = (const int*)d_in[3];
    const int*   ei     = (const int*)d_in[4];
    const int*   ncid   = (const int*)d_in[5];
    const float* embO   = (const float*)d_in[6];
    const float* embL   = (const float*)d_in[7];
    const float* lin1W  = (const float*)d_in[8];
    const float* lin1b  = (const float*)d_in[9];
    const float* ca1W1  = (const float*)d_in[10];
    const float* ca1b1  = (const float*)d_in[11];
    const float* ca1W2  = (const float*)d_in[12];
    const float* ca1b2  = (const float*)d_in[13];
    const float* lin2W  = (const float*)d_in[14];
    const float* lin2b  = (const float*)d_in[15];
    const float* ca2W1  = (const float*)d_in[16];
    const float* ca2b1  = (const float*)d_in[17];
    const float* ca2W2  = (const float*)d_in[18];
    const float* ca2b2  = (const float*)d_in[19];
    const float* sageWl = (const float*)d_in[20];
    const float* sagebl = (const float*)d_in[21];
    const float* sageWr = (const float*)d_in[22];
    const float* scaW1  = (const float*)d_in[23];
    const float* scab1  = (const float*)d_in[24];
    const float* scaW2  = (const float*)d_in[25];
    const float* scab2  = (const float*)d_in[26];
    const float* clsW   = (const float*)d_in[27];
    const float* clsb   = (const float*)d_in[28];
    float* out = (float*)d_out;

    // ---- workspace carve-up ----
    char* w = (char*)d_ws;
    size_t o = 0;
    auto take = [&](size_t bytes) { char* p = w + o; o = alup(o + bytes); return p; };
    float* base    = (float*)take((size_t)N_ * 256 * 4);
    float* feat162 = (float*)take((size_t)N_ * 176 * 4);
    float* W162    = (float*)take((size_t)176 * 256 * 4);
    float* T       = (float*)take((size_t)18 * 8 * 256 * 4);
    float* csum    = (float*)take((size_t)256 * 4);
    float* stats   = (float*)take((size_t)6 * 8192 * 4);
    float* invcnt  = (float*)take((size_t)N_ * 4);
    int*   cnt     = (int*)take((size_t)N_ * 4);
    int*   off     = (int*)take((size_t)(N_ + 1) * 4);
    int*   cursor  = (int*)take((size_t)N_ * 4);
    int*   csr     = (int*)take((size_t)E_ * 4);
    int*   cfgpos  = (int*)take((size_t)N_ * 4);
    u16*   Wt2     = (u16*)take((size_t)256 * 256 * 2);
    u16*   Wfold   = (u16*)take((size_t)C_ * 256 * 512 * 2);   // 4 MB
    float* biasF   = (float*)take((size_t)C_ * 256 * 4);
    u16*   CAW1    = (u16*)take((size_t)5 * 8192 * 2);         // packed frag order
    u16*   CAW2    = (u16*)take((size_t)5 * 8192 * 2);

    const size_t slab = (size_t)SZ_ * 2;                       // bf16: 5.12 MB
    size_t avail = (ws_size > o) ? (ws_size - o) : 0;
    int Cc = (int)(avail / (3 * slab + 768));
    if (Cc > C_) Cc = C_;
    if (Cc < 1) Cc = 1;
    u16* BufH = (u16*)take((size_t)Cc * slab);
    u16* BufY = (u16*)take((size_t)Cc * slab);
    u16* BufA = (u16*)take((size_t)Cc * slab);
    (void)in_sizes; (void)n_in; (void)out_size;

    auto S = [&](int s) { return stats + (size_t)s * 8192; };
    auto Q = [&](int s) { return stats + (size_t)s * 8192 + 4096; };

    hipMemsetAsync(stats, 0, 6 * 8192 * 4, stream);
    hipMemsetAsync(cnt, 0, N_ * 4, stream);
    hipMemsetAsync(cfgpos, 0xFF, N_ * 4, stream);

    // shared prep
    tbl_k<<<144, 256, 0, stream>>>(embL, lin1W, T);
    csum_k<<<1, 256, 0, stream>>>(T, csum);
    feat_k<<<N_, 192, 0, stream>>>(xfeat, xlay, xop, embL, embO, feat162);
    wpack_k<<<176, 256, 0, stream>>>(lin1W, W162);
    wt2_k<<<256, 256, 0, stream>>>(lin2W, Wt2);
    packw1_k<<<32, 256, 0, stream>>>(ca1W1, CAW1 + 0 * 8192);
    packw1_k<<<32, 256, 0, stream>>>(ca2W1, CAW1 + 1 * 8192);
    packw1_k<<<32, 256, 0, stream>>>(scaW1 + 0 * 8192, CAW1 + 2 * 8192);
    packw1_k<<<32, 256, 0, stream>>>(scaW1 + 1 * 8192, CAW1 + 3 * 8192);
    packw1_k<<<32, 256, 0, stream>>>(scaW1 + 2 * 8192, CAW1 + 4 * 8192);
    packw2_k<<<32, 256, 0, stream>>>(ca1W2, CAW2 + 0 * 8192);
    packw2_k<<<32, 256, 0, stream>>>(ca2W2, CAW2 + 1 * 8192);
    packw2_k<<<32, 256, 0, stream>>>(scaW2 + 0 * 8192, CAW2 + 2 * 8192);
    packw2_k<<<32, 256, 0, stream>>>(scaW2 + 1 * 8192, CAW2 + 3 * 8192);
    packw2_k<<<32, 256, 0, stream>>>(scaW2 + 2 * 8192, CAW2 + 4 * 8192);
    cfgpos_k<<<(NC_ + 255) / 256, 256, 0, stream>>>(ncid, cfgpos);
    hist_k<<<(E_ + 255) / 256, 256, 0, stream>>>(ei, cnt);
    scan_k<<<1, 1024, 0, stream>>>(cnt, off, cursor, invcnt);
    fill_k<<<(E_ + 255) / 256, 256, 0, stream>>>(ei, cursor, csr);

    // base = feat162 @ W162 + lin1_b (fp32, one-time)
    gemm_k<<<dim3(2, 79, 1), 256, 0, stream>>>(feat162, 176, W162, 176, lin1b, base, N_);

    // ---- per-config-chunk pipeline ----
    for (int c0 = 0; c0 < C_; c0 += Cc) {
        const int nc = (C_ - c0 < Cc) ? (C_ - c0) : Cc;
        const int co = c0 * 256;

        lin1_cfg_k<<<dim3(NC_ / 16, 1, nc), 256, 0, stream>>>(
            base, T, ncid, xcfg + (size_t)c0 * NC_ * 18, BufH, S(0) + co, Q(0) + co);
        lin1_unc_k<<<625, 256, 0, stream>>>(
            base, csum, cfgpos, nc, BufH, S(0) + co, Q(0) + co);

        apply_k<1, 0, 0><<<dim3(625, 1, nc), 512, 0, stream>>>(
            BufH, BufH, nullptr, CAW1 + 0 * 8192, ca1b1, CAW2 + 0 * 8192, ca1b2,
            S(0) + co, Q(0) + co, nullptr, nullptr);

        mgemm_k<1><<<dim3(2, 79, nc), 256, 0, stream>>>(
            BufH, SZ_, nullptr, 0, Wt2, 0, 256, 256,
            lin2b, 0, BufY, SZ_, N_, S(1) + co, Q(1) + co);

        apply_k<1, 0, 1><<<dim3(625, 1, nc), 512, 0, stream>>>(
            BufY, BufY, nullptr, CAW1 + 1 * 8192, ca2b1, CAW2 + 1 * 8192, ca2b2,
            S(1) + co, Q(1) + co, S(2) + co, Q(2) + co);

        for (int i = 0; i < 3; ++i) {
            const int set = 2 + i;
            foldw_k<<<dim3(256, nc), 256, 0, stream>>>(
                sageWl + (size_t)i * 65536, sageWr + (size_t)i * 65536, sagebl + i * 256,
                S(set) + co, Q(set) + co,
                Wfold + (size_t)c0 * 256 * 512, biasF + co);
            agg_k<<<nc * 2500, 256, 0, stream>>>(BufY, off, csr, invcnt,
                                                 S(set) + co, BufA);
            if (i < 2) {
                msage_k<1><<<dim3(157, nc), 512, 0, stream>>>(
                    BufA, BufY, Wfold + (size_t)c0 * 256 * 512, 256 * 512, biasF + co,
                    CAW1 + (2 + i) * 8192, scab1 + i * 32,
                    CAW2 + (2 + i) * 8192, scab2 + i * 256,
                    BufY, N_, S(3 + i) + co, Q(3 + i) + co);
            } else {
                msage_k<2><<<dim3(157, nc), 512, 0, stream>>>(
                    BufA, BufY, Wfold + (size_t)c0 * 256 * 512, 256 * 512, biasF + co,
                    CAW1 + (2 + i) * 8192, scab1 + i * 32,
                    CAW2 + (2 + i) * 8192, scab2 + i * 256,
                    BufY, N_, S(5) + co, nullptr);
            }
        }
    }

    cls_k<<<16, 256, 0, stream>>>(S(5), clsW, clsb, out);
}

// Round 18
// 1152.995 us; speedup vs baseline: 1.0030x; 1.0030x over previous
//
#include <hip/hip_runtime.h>
#include <hip/hip_bf16.h>
#include <math.h>

// ---------------- problem constants ----------------
constexpr int C_  = 16;
constexpr int N_  = 10000;
constexpr int NC_ = 2000;
constexpr int E_  = 50000;
constexpr int D_  = 256;
constexpr int SZ_ = N_ * D_;          // per-config slab (elements)
constexpr float EPS_ = 1e-5f;

typedef unsigned short u16;
typedef __attribute__((ext_vector_type(8))) unsigned short us8v;
typedef __attribute__((ext_vector_type(4))) unsigned short us4v;
typedef __attribute__((ext_vector_type(8))) short s16x8;
typedef __attribute__((ext_vector_type(4))) float f32x4;

typedef __attribute__((address_space(3))) unsigned int lds_uint;
typedef const __attribute__((address_space(1))) unsigned int glb_uint;

__device__ __forceinline__ u16 f2bf(float f) {
    __hip_bfloat16 h = __float2bfloat16(f);   // hw v_cvt (RNE)
    return __builtin_bit_cast(u16, h);
}
__device__ __forceinline__ float bf2f(u16 h) {
    return __uint_as_float(((unsigned)h) << 16);
}
// fast gelu: erf via Abramowitz-Stegun 7.1.26 (|err|<=1.5e-7) + hw exp
__device__ __forceinline__ float gelu_f(float x) {
    float z = x * 0.70710678118654752f;
    float az = fabsf(z);
    float t = 1.f / fmaf(0.3275911f, az, 1.f);
    float p = t * (0.254829592f + t * (-0.284496736f + t * (1.421413741f +
              t * (-1.453152027f + t * 1.061405429f))));
    float e = p * __expf(-z * z);
    float erfv = (z >= 0.f) ? (1.f - e) : (e - 1.f);
    return 0.5f * x * (1.f + erfv);
}

// ---------------- tiny prep kernels ----------------

__global__ __launch_bounds__(256) void tbl_k(const float* __restrict__ embL,
                                             const float* __restrict__ W,
                                             float* __restrict__ T) {
    int b = blockIdx.x;            // 0..143
    int s = b >> 3, i = b & 7, d = threadIdx.x;
    float acc = 0.f;
#pragma unroll
    for (int k = 0; k < 4; ++k)
        acc = fmaf(embL[i * 4 + k], W[(134 + s * 4 + k) * 256 + d], acc);
    T[(s * 8 + i) * 256 + d] = acc;
}

// csum[d] = sum_s T[s][0][d]
__global__ __launch_bounds__(256) void csum_k(const float* __restrict__ T,
                                              float* __restrict__ cs) {
    int d = threadIdx.x;
    float a = 0.f;
#pragma unroll
    for (int s = 0; s < 18; ++s) a += T[(s * 8) * 256 + d];
    cs[d] = a;
}

__global__ __launch_bounds__(192) void feat_k(const float* __restrict__ xf,
                                              const int* __restrict__ xlay,
                                              const int* __restrict__ xop,
                                              const float* __restrict__ embL,
                                              const float* __restrict__ embO,
                                              float* __restrict__ f) {
    int n = blockIdx.x, j = threadIdx.x;
    if (j >= 176) return;
    float v;
    if (j < 134) v = xf[n * 134 + j];
    else if (j < 158) { int q = j - 134; int t = q >> 2, k = q & 3; v = embL[(xlay[n * 6 + t] + 2) * 4 + k]; }
    else if (j < 162) { int k = j - 158; v = embO[xop[n] * 4 + k]; }
    else v = 0.f;
    f[n * 176 + j] = v;
}

__global__ __launch_bounds__(256) void wpack_k(const float* __restrict__ W,
                                               float* __restrict__ Wp) {
    int j = blockIdx.x, d = threadIdx.x;
    float v = 0.f;
    if (j < 134) v = W[j * 256 + d];
    else if (j < 158) v = W[(206 + j - 134) * 256 + d];
    else if (j < 162) v = W[(230 + j - 158) * 256 + d];
    Wp[j * 256 + d] = v;
}

// pack channel-attn W1 [256][32] into MFMA fragment order
__global__ __launch_bounds__(256) void packw1_k(const float* __restrict__ W1,
                                                u16* __restrict__ dst) {
    int i = blockIdx.x * 256 + threadIdx.x;    // 0..8191
    int j = i & 7, lane = (i >> 3) & 63, half = (i >> 9) & 1, ks = (i >> 10) & 1, wid = (i >> 11) & 3;
    int k = wid * 64 + ks * 32 + ((lane >> 4) << 3) + j;
    int col = half * 16 + (lane & 15);
    dst[i] = f2bf(W1[k * 32 + col]);
}
// pack channel-attn W2 [32][256] into MFMA fragment order
__global__ __launch_bounds__(256) void packw2_k(const float* __restrict__ W2,
                                                u16* __restrict__ dst) {
    int i = blockIdx.x * 256 + threadIdx.x;    // 0..8191
    int j = i & 7, lane = (i >> 3) & 63, q = (i >> 9) & 3, wid = (i >> 11) & 3;
    int kq = lane >> 4, cl = lane & 15;
    dst[i] = f2bf(W2[(kq * 8 + j) * 256 + (wid * 4 + q) * 16 + cl]);
}

__global__ __launch_bounds__(256) void cfgpos_k(const int* __restrict__ ncid,
                                                int* __restrict__ cfgpos) {
    int i = blockIdx.x * 256 + threadIdx.x;
    if (i < NC_) cfgpos[ncid[i]] = i;
}

__global__ __launch_bounds__(256) void hist_k(const int* __restrict__ ei, int* __restrict__ cnt) {
    int e = blockIdx.x * 256 + threadIdx.x;
    if (e < E_) atomicAdd(&cnt[ei[E_ + e]], 1);
}

__global__ __launch_bounds__(1024) void scan_k(const int* __restrict__ cnt,
                                               int* __restrict__ off,
                                               int* __restrict__ cursor,
                                               float* __restrict__ invcnt) {
    __shared__ int s[1024];
    int t = threadIdx.x;
    int base = t * 10;
    int local[10];
    int part = 0;
#pragma unroll
    for (int k = 0; k < 10; ++k) {
        int idx = base + k;
        int v = (idx < N_) ? cnt[idx] : 0;
        local[k] = v; part += v;
    }
    s[t] = part;
    __syncthreads();
    for (int o = 1; o < 1024; o <<= 1) {
        int val = (t >= o) ? s[t - o] : 0;
        __syncthreads();
        s[t] += val;
        __syncthreads();
    }
    int pre = s[t] - part;
#pragma unroll
    for (int k = 0; k < 10; ++k) {
        int idx = base + k;
        if (idx < N_) {
            off[idx] = pre;
            cursor[idx] = pre;
            invcnt[idx] = 1.0f / (float)(local[k] > 1 ? local[k] : 1);
            pre += local[k];
        }
    }
    if (t == 1023) off[N_] = s[1023];
}

__global__ __launch_bounds__(256) void fill_k(const int* __restrict__ ei,
                                              int* __restrict__ cursor,
                                              int* __restrict__ csr) {
    int e = blockIdx.x * 256 + threadIdx.x;
    if (e < E_) {
        int t = ei[E_ + e];
        int p = atomicAdd(&cursor[t], 1);
        csr[p] = ei[e];
    }
}

// transpose lin2_W -> Wt2[j][k] bf16
__global__ __launch_bounds__(256) void wt2_k(const float* __restrict__ W,
                                             u16* __restrict__ Wt) {
    int j = blockIdx.x, k = threadIdx.x;
    Wt[j * 256 + k] = f2bf(W[k * 256 + j]);
}

// fold instance-norm into sage weights (per config); stats computed inline
__global__ __launch_bounds__(256) void foldw_k(const float* __restrict__ Wl,
                                               const float* __restrict__ Wr,
                                               const float* __restrict__ bl,
                                               const float* __restrict__ nssum,
                                               const float* __restrict__ nssq,
                                               u16* __restrict__ Wt,
                                               float* __restrict__ biasF) {
    __shared__ float red[256];
    int c = blockIdx.y, j = blockIdx.x, k = threadIdx.x;
    float m = nssum[c * 256 + k] * (1.0f / (float)N_);
    float v = nssq[c * 256 + k] * (1.0f / (float)N_) - m * m;
    float rsv = rsqrtf(v + EPS_);
    float muv = m;
    float fl = rsv * Wl[k * 256 + j];
    float fr = rsv * Wr[k * 256 + j];
    size_t wb = ((size_t)c * 256 + j) * 512;
    Wt[wb + k] = f2bf(fl);
    Wt[wb + 256 + k] = f2bf(fr);
    red[k] = muv * (fl + fr);
    __syncthreads();
    for (int s = 128; s > 0; s >>= 1) {
        if (k < s) red[k] += red[k + s];
        __syncthreads();
    }
    if (k == 0) biasF[c * 256 + j] = bl[j] - red[0];
}

// ---------------- lin1 (configured nodes) ----------------
__global__ __launch_bounds__(256) void lin1_cfg_k(const float* __restrict__ base,
                                                  const float* __restrict__ T,
                                                  const int* __restrict__ ncid,
                                                  const int* __restrict__ xcfg,
                                                  u16* __restrict__ H,
                                                  float* __restrict__ ssum,
                                                  float* __restrict__ ssq) {
    __shared__ int idxs[16][18];   // premultiplied by 256
    __shared__ int nid[16];
    const int c = blockIdx.z, j0 = blockIdx.x * 16, tid = threadIdx.x;
    if (tid < 16) nid[tid] = ncid[j0 + tid];
    for (int t = tid; t < 288; t += 256) {
        int row = t / 18, s = t - row * 18;
        idxs[row][s] = (xcfg[((size_t)c * NC_ + j0 + row) * 18 + s] + 2) * 256;
    }
    __syncthreads();
    const int d = tid;
    float psum = 0.f, psq = 0.f;
    for (int g = 0; g < 16; g += 4) {
        float acc[4];
#pragma unroll
        for (int gg = 0; gg < 4; ++gg) acc[gg] = base[(size_t)nid[g + gg] * 256 + d];
#pragma unroll
        for (int s = 0; s < 18; ++s) {
            const float* Ts = &T[s * 2048 + d];
#pragma unroll
            for (int gg = 0; gg < 4; ++gg)
                acc[gg] += Ts[idxs[g + gg][s]];
        }
#pragma unroll
        for (int gg = 0; gg < 4; ++gg) {
            H[((size_t)c * N_ + nid[g + gg]) * 256 + d] = f2bf(acc[gg]);
            psum += acc[gg]; psq += acc[gg] * acc[gg];
        }
    }
    atomicAdd(&ssum[c * 256 + d], psum);
    atomicAdd(&ssq[c * 256 + d], psq);
}

// ---------------- lin1 (unconfigured nodes) ----------------
__global__ __launch_bounds__(256) void lin1_unc_k(const float* __restrict__ base,
                                                  const float* __restrict__ csum,
                                                  const int* __restrict__ cfgpos,
                                                  int nc,
                                                  u16* __restrict__ H,
                                                  float* __restrict__ ssum,
                                                  float* __restrict__ ssq) {
    __shared__ float red[2048];
    const int n0 = blockIdx.x * 16, tid = threadIdx.x;
    float ps[8] = {0, 0, 0, 0, 0, 0, 0, 0}, pq[8] = {0, 0, 0, 0, 0, 0, 0, 0};
#pragma unroll
    for (int it = 0; it < 2; ++it) {
        const int flat = tid + it * 256;
        const int row = flat >> 5, cb = (flat & 31) * 8;
        const int n = n0 + row;
        if (cfgpos[n] >= 0) continue;
        us8v b;
#pragma unroll
        for (int j = 0; j < 8; ++j) {
            float v = base[(size_t)n * 256 + cb + j] + csum[cb + j];
            b[j] = f2bf(v);
            ps[j] += v; pq[j] += v * v;
        }
        for (int c = 0; c < nc; ++c)
            *(us8v*)&H[((size_t)c * N_ + n) * 256 + cb] = b;
    }
#pragma unroll
    for (int j = 0; j < 8; ++j)
        red[((tid >> 5) * 32 + (tid & 31)) * 8 + j] = ps[j];
    __syncthreads();
    {
        const int cb2 = tid >> 3, j2 = tid & 7;
        float s = 0.f;
#pragma unroll
        for (int r8 = 0; r8 < 8; ++r8) s += red[(r8 * 32 + cb2) * 8 + j2];
        for (int c = 0; c < nc; ++c) atomicAdd(&ssum[c * 256 + tid], s);
    }
    __syncthreads();
#pragma unroll
    for (int j = 0; j < 8; ++j)
        red[((tid >> 5) * 32 + (tid & 31)) * 8 + j] = pq[j];
    __syncthreads();
    {
        const int cb2 = tid >> 3, j2 = tid & 7;
        float s = 0.f;
#pragma unroll
        for (int r8 = 0; r8 < 8; ++r8) s += red[(r8 * 32 + cb2) * 8 + j2];
        for (int c = 0; c < nc; ++c) atomicAdd(&ssq[c * 256 + tid], s);
    }
}

// ---------------- CSR gather-mean: vector index load + shfl broadcast ----------------
// deg-0 rows write mu computed inline from ssum
__global__ __launch_bounds__(256) void agg_k(const u16* __restrict__ H,
                                             const int* __restrict__ off,
                                             const int* __restrict__ csr,
                                             const float* __restrict__ invcnt,
                                             const float* __restrict__ nssum,
                                             u16* __restrict__ Agg) {
    int wave = threadIdx.x >> 6, lane = threadIdx.x & 63;
    int pair = blockIdx.x * 4 + wave;
    int c = pair / N_, t = pair - c * N_;
    int d4 = lane * 4;
    int o0 = off[t], o1 = off[t + 1];
    int deg = o1 - o0;
    us4v o;
    if (deg > 0) {
        int myidx = (lane < deg) ? csr[o0 + lane] : 0;
        const u16* Hc = H + (size_t)c * SZ_ + d4;
        float ax = 0.f, ay = 0.f, az = 0.f, aw = 0.f;
        int lim = deg < 64 ? deg : 64;
        int i = 0;
        for (; i + 4 <= lim; i += 4) {
            int s0 = __shfl(myidx, i), s1 = __shfl(myidx, i + 1);
            int s2 = __shfl(myidx, i + 2), s3 = __shfl(myidx, i + 3);
            us4v h0 = *(const us4v*)&Hc[(size_t)s0 * 256];
            us4v h1 = *(const us4v*)&Hc[(size_t)s1 * 256];
            us4v h2 = *(const us4v*)&Hc[(size_t)s2 * 256];
            us4v h3 = *(const us4v*)&Hc[(size_t)s3 * 256];
            ax += (bf2f(h0.x) + bf2f(h1.x)) + (bf2f(h2.x) + bf2f(h3.x));
            ay += (bf2f(h0.y) + bf2f(h1.y)) + (bf2f(h2.y) + bf2f(h3.y));
            az += (bf2f(h0.z) + bf2f(h1.z)) + (bf2f(h2.z) + bf2f(h3.z));
            aw += (bf2f(h0.w) + bf2f(h1.w)) + (bf2f(h2.w) + bf2f(h3.w));
        }
        for (; i < lim; ++i) {
            int s = __shfl(myidx, i);
            us4v h = *(const us4v*)&Hc[(size_t)s * 256];
            ax += bf2f(h.x); ay += bf2f(h.y); az += bf2f(h.z); aw += bf2f(h.w);
        }
        for (int j = o0 + 64; j < o1; ++j) {     // rare: degree > 64
            int s = csr[j];
            us4v h = *(const us4v*)&Hc[(size_t)s * 256];
            ax += bf2f(h.x); ay += bf2f(h.y); az += bf2f(h.z); aw += bf2f(h.w);
        }
        float inv = invcnt[t];
        o.x = f2bf(ax * inv); o.y = f2bf(ay * inv);
        o.z = f2bf(az * inv); o.w = f2bf(aw * inv);
    } else {
        const float invN = 1.0f / (float)N_;
        o.x = f2bf(nssum[c * 256 + d4 + 0] * invN);
        o.y = f2bf(nssum[c * 256 + d4 + 1] * invN);
        o.z = f2bf(nssum[c * 256 + d4 + 2] * invN);
        o.w = f2bf(nssum[c * 256 + d4 + 3] * invN);
    }
    *(us4v*)&Agg[((size_t)c * N_ + t) * 256 + d4] = o;
}

// ---------------- bf16 MFMA GEMM (128x128 tile, 2-phase dbuf): Y = [A1|A2] @ Wt^T + bias ----------------
template <int STATS>
__global__ __launch_bounds__(256) void mgemm_k(
    const u16* __restrict__ A1, size_t sA1,
    const u16* __restrict__ A2, size_t sA2,
    const u16* __restrict__ Wt, size_t sW, int K1, int Ktot,
    const float* __restrict__ bias, size_t sBias,
    u16* __restrict__ Y, size_t sY, int Mrows,
    float* __restrict__ ssum, float* __restrict__ ssq)
{
    __shared__ __align__(16) char SM[65536];   // 2 x (A 16KB + B 16KB)
    const int tid = threadIdx.x;
    const int lane = tid & 63, wid = tid >> 6;
    const int wr = wid >> 1, wc = wid & 1;

    // XCD-aware bijective remap of the flattened block id
    const int gx = gridDim.x, gy = gridDim.y;
    int nwg = gx * gy * gridDim.z;
    int orig = blockIdx.x + gx * (blockIdx.y + gy * blockIdx.z);
    int q = nwg >> 3, r = nwg & 7;
    int xcd = orig & 7, idx = orig >> 3;
    int swz = (xcd < r ? xcd * (q + 1) : r * (q + 1) + (xcd - r) * q) + idx;
    const int bx = swz % gx;
    const int tmp = swz / gx;
    const int by = tmp % gy;
    const int c  = tmp / gy;

    const int rowbase = by * 128, colbase = bx * 128;

    const u16* A1p = A1 + (size_t)c * sA1;
    const u16* A2p = A2 ? (A2 + (size_t)c * sA2) : nullptr;
    const u16* Wp  = Wt + (size_t)c * sW;

    f32x4 acc[4][4];
#pragma unroll
    for (int i = 0; i < 4; ++i)
#pragma unroll
        for (int j = 0; j < 4; ++j) acc[i][j] = (f32x4)0.f;

    auto stage = [&](int buf, int k0) {
        const u16* asrc; int ak;
        if (k0 < K1) { asrc = A1p; ak = k0; } else { asrc = A2p; ak = k0 - K1; }
        u16* Ab = (u16*)(SM + buf * 32768);
        u16* Bb = (u16*)(SM + buf * 32768 + 16384);
#pragma unroll
        for (int jj = 0; jj < 4; ++jj) {
            const int u = tid + jj * 256;
            const int row = u >> 3, chunk = u & 7;
            const int sc2 = chunk ^ (row & 7);
            int garow = rowbase + row;
            if (garow >= Mrows) garow = Mrows - 1;             // clamp: values unused
            __builtin_amdgcn_global_load_lds(
                (glb_uint*)(asrc + (size_t)garow * 256 + ak + sc2 * 8),
                (lds_uint*)(Ab + u * 8), 16, 0, 0);
            __builtin_amdgcn_global_load_lds(
                (glb_uint*)(Wp + (size_t)(colbase + row) * Ktot + k0 + sc2 * 8),
                (lds_uint*)(Bb + u * 8), 16, 0, 0);
        }
    };

    const int nsteps = Ktot >> 6;
    stage(0, 0);
    __syncthreads();                 // drain prologue (implicit vmcnt(0))
    int cur = 0;
    for (int t = 0; t < nsteps; ++t) {
        if (t + 1 < nsteps) stage(cur ^ 1, (t + 1) * 64);   // overlap with MFMA
        const u16* Asm = (const u16*)(SM + cur * 32768);
        const u16* Bsm = (const u16*)(SM + cur * 32768 + 16384);
#pragma unroll
        for (int ks = 0; ks < 2; ++ks) {
            s16x8 aF[4], bF[4];
            const int kk = ks * 32 + ((lane >> 4) << 3);
#pragma unroll
            for (int f = 0; f < 4; ++f) {
                int ar = wr * 64 + f * 16 + (lane & 15);
                aF[f] = *(const s16x8*)&Asm[(ar * 64 + kk) ^ ((ar & 7) << 3)];
                int br = wc * 64 + f * 16 + (lane & 15);
                bF[f] = *(const s16x8*)&Bsm[(br * 64 + kk) ^ ((br & 7) << 3)];
            }
#pragma unroll
            for (int fr = 0; fr < 4; ++fr)
#pragma unroll
                for (int fc = 0; fc < 4; ++fc)
                    acc[fr][fc] = __builtin_amdgcn_mfma_f32_16x16x32_bf16(
                        aF[fr], bF[fc], acc[fr][fc], 0, 0, 0);
        }
        __syncthreads();             // next buf staged, cur reads done
        cur ^= 1;
    }

    float bcol[4];
#pragma unroll
    for (int fc = 0; fc < 4; ++fc)
        bcol[fc] = bias[(size_t)c * sBias + colbase + wc * 64 + fc * 16 + (lane & 15)];
    u16* Yp = Y + (size_t)c * sY;
    float ps[4] = {0, 0, 0, 0}, pq[4] = {0, 0, 0, 0};
#pragma unroll
    for (int fr = 0; fr < 4; ++fr) {
#pragma unroll
        for (int i = 0; i < 4; ++i) {
            int grow = rowbase + wr * 64 + fr * 16 + ((lane >> 4) << 2) + i;
            if (grow < Mrows) {
                size_t rb = (size_t)grow * 256 + colbase + wc * 64 + (lane & 15);
#pragma unroll
                for (int fc = 0; fc < 4; ++fc) {
                    float v = acc[fr][fc][i] + bcol[fc];
                    Yp[rb + fc * 16] = f2bf(v);
                    if (STATS) { ps[fc] += v; pq[fc] += v * v; }
                }
            }
        }
    }
    if (STATS) {
#pragma unroll
        for (int fc = 0; fc < 4; ++fc) {
            float s = ps[fc], q2 = pq[fc];
            s += __shfl_xor(s, 16); s += __shfl_xor(s, 32);
            q2 += __shfl_xor(q2, 16); q2 += __shfl_xor(q2, 32);
            if (lane < 16) {
                int col = colbase + wc * 64 + fc * 16 + lane;
                atomicAdd(&ssum[c * 256 + col], s);
                atomicAdd(&ssq[c * 256 + col], q2);
            }
        }
    }
}

// ---------------- FUSED sage: Y = gelu(chattn([Agg|H] @ Wfold^T + biasF) + H) ----------------
// 64 rows x 256 cols tile, K=512 in 16 steps of 32, 512 threads / 8 waves.
// Double-buffered staging, 20KB/buf -> LDS 40KB -> 4 blocks/CU = 32 waves/CU.
// Chunk swizzle uses ((r>>1)&3): with 16-bank row stride this spans all 8
// chunk-slots over any 16 consecutive rows -> 2-way (free) ds_read_b128.
template <int SMODE>   // 1: sum+sumsq, 2: sum only
__global__ __launch_bounds__(512) void msage_k(
    const u16* __restrict__ A1,                 // Agg slabs
    const u16* __restrict__ A2,                 // H slabs (also residual, in-place out)
    const u16* __restrict__ Wt, size_t sW,      // folded weights [256][512] per config
    const float* __restrict__ biasF,            // [nc][256]
    const u16* __restrict__ W1p, const float* __restrict__ b1,
    const u16* __restrict__ W2p, const float* __restrict__ b2,
    u16* __restrict__ Yout, int Mrows,
    float* __restrict__ ssum, float* __restrict__ ssq)
{
    __shared__ __align__(16) char SM[40960];
    // buf b: A at b*20480 (4096 B, 64x32), B at b*20480+4096 (16384 B, 256x32)
    u16*   xbf = (u16*)SM;                      // 64x264  (epilogue, aliases bufs)
    u16*   tbf = (u16*)(SM + 33792);            // 64x40   (epilogue)
    float* red = (float*)SM;                    // stats reduce (aliases dead xbf)

    const int tid = threadIdx.x;
    const int lane = tid & 63, w = tid >> 6;     // wave 0..7 (col-32 slice)
    const int cl = lane & 15, kq = lane >> 4;

    // XCD-aware bijective remap over (by, c)
    int nwg = gridDim.x * gridDim.y;
    int orig = blockIdx.x + gridDim.x * blockIdx.y;
    int q = nwg >> 3, r = nwg & 7;
    int xcd = orig & 7, idx = orig >> 3;
    int swz = (xcd < r ? xcd * (q + 1) : r * (q + 1) + (xcd - r) * q) + idx;
    const int by = swz % gridDim.x;
    const int c  = swz / gridDim.x;
    const int rowbase = by * 64;

    const u16* A1p = A1 + (size_t)c * SZ_;
    const u16* A2p = A2 + (size_t)c * SZ_;
    const u16* Wp  = Wt + (size_t)c * sW;

    f32x4 acc[4][2];
#pragma unroll
    for (int i = 0; i < 4; ++i)
#pragma unroll
        for (int j = 0; j < 2; ++j) acc[i][j] = (f32x4)0.f;

    // K-step = 32: A tile 64x32 (256 16B units), B tile 256x32 (1024 units)
    auto stage = [&](int buf, int k0) {
        const u16* asrc = (k0 < 256) ? A1p : A2p;
        const int ak = (k0 < 256) ? k0 : (k0 - 256);
        u16* Ab = (u16*)(SM + buf * 20480);
        u16* Bb = (u16*)(SM + buf * 20480 + 4096);
        // A: 256 units, threads 0..255 (waves 0..3), 1/thread
        if (tid < 256) {
            const int row = tid >> 2, chunk = tid & 3;
            const int sc2 = chunk ^ ((row >> 1) & 3);
            int garow = rowbase + row;
            if (garow >= Mrows) garow = Mrows - 1;
            __builtin_amdgcn_global_load_lds(
                (glb_uint*)(asrc + (size_t)garow * 256 + ak + sc2 * 8),
                (lds_uint*)(Ab + tid * 8), 16, 0, 0);
        }
        // B: 1024 units, 2/thread
#pragma unroll
        for (int jj = 0; jj < 2; ++jj) {
            const int u = tid + jj * 512;
            const int wcol = u >> 2, chunk = u & 3;
            const int sc2 = chunk ^ ((wcol >> 1) & 3);
            __builtin_amdgcn_global_load_lds(
                (glb_uint*)(Wp + (size_t)wcol * 512 + k0 + sc2 * 8),
                (lds_uint*)(Bb + u * 8), 16, 0, 0);
        }
    };

    // ---- 2-phase pipelined K loop: Ktot = 512, 16 steps of 32 ----
    stage(0, 0);
    __syncthreads();                 // drain prologue stage (implicit vmcnt(0))
    int cur = 0;
    for (int t = 0; t < 16; ++t) {
        if (t < 15) stage(cur ^ 1, (t + 1) * 32);   // overlap with MFMA below
        const u16* Asm = (const u16*)(SM + cur * 20480);
        const u16* Bsm = (const u16*)(SM + cur * 20480 + 4096);
        {
            s16x8 aF[4], bF[2];
            const int kk = kq * 8;
#pragma unroll
            for (int f = 0; f < 4; ++f) {
                const int ar = f * 16 + cl;
                aF[f] = *(const s16x8*)&Asm[(ar * 32 + kk) ^ (((ar >> 1) & 3) << 3)];
            }
#pragma unroll
            for (int fc = 0; fc < 2; ++fc) {
                const int bc = w * 32 + fc * 16 + cl;
                bF[fc] = *(const s16x8*)&Bsm[(bc * 32 + kk) ^ (((bc >> 1) & 3) << 3)];
            }
#pragma unroll
            for (int fr = 0; fr < 4; ++fr)
#pragma unroll
                for (int fc = 0; fc < 2; ++fc)
                    acc[fr][fc] = __builtin_amdgcn_mfma_f32_16x16x32_bf16(
                        aF[fr], bF[fc], acc[fr][fc], 0, 0, 0);
        }
        __syncthreads();             // drains vmcnt(0): next buf ready, cur reads done
        cur ^= 1;
    }

    float bcol[2];
#pragma unroll
    for (int fc = 0; fc < 2; ++fc)
        bcol[fc] = biasF[c * 256 + w * 32 + fc * 16 + cl];

    // ---- attention epilogue ----
#pragma unroll
    for (int fr = 0; fr < 4; ++fr)
#pragma unroll
        for (int i = 0; i < 4; ++i) {
            const int rloc = fr * 16 + kq * 4 + i;
#pragma unroll
            for (int fc = 0; fc < 2; ++fc)
                xbf[rloc * 264 + w * 32 + fc * 16 + cl] =
                    f2bf(acc[fr][fc][i] + bcol[fc]);
        }
    __syncthreads();
    // t = relu(x@W1 + b1): wave = (rb = w>>1 row-block, ch = w&1 col-half), K=256
    {
        const int rb = w >> 1, ch = w & 1;
        f32x4 at = (f32x4)0.f;
#pragma unroll
        for (int s = 0; s < 8; ++s) {
            s16x8 aF = *(const s16x8*)&xbf[(rb * 16 + cl) * 264 + s * 32 + kq * 8];
            s16x8 bF = *(const s16x8*)&W1p[((s * 2 + ch) * 64 + lane) * 8];
            at = __builtin_amdgcn_mfma_f32_16x16x32_bf16(aF, bF, at, 0, 0, 0);
        }
        const float b1v = b1[ch * 16 + cl];
#pragma unroll
        for (int i = 0; i < 4; ++i)
            tbf[(rb * 16 + kq * 4 + i) * 40 + ch * 16 + cl] =
                f2bf(fmaxf(at[i] + b1v, 0.f));
    }
    __syncthreads();
    // y' = sigmoid(t@W2 + b2) * x  -> back into xbf (wave = col-32 slice, 2 col frags)
    {
        s16x8 aF[4];
#pragma unroll
        for (int rg = 0; rg < 4; ++rg)
            aF[rg] = *(const s16x8*)&tbf[(rg * 16 + cl) * 40 + kq * 8];
#pragma unroll
        for (int q2 = 0; q2 < 2; ++q2) {
            const int cf = w * 2 + q2;            // 0..15
            const int colb = cf * 16;
            s16x8 bF = *(const s16x8*)&W2p[(cf * 64 + lane) * 8];
            const float b2v = b2[colb + cl];
#pragma unroll
            for (int rg = 0; rg < 4; ++rg) {
                f32x4 a2 = __builtin_amdgcn_mfma_f32_16x16x32_bf16(
                    aF[rg], bF, (f32x4)0.f, 0, 0, 0);
#pragma unroll
                for (int i = 0; i < 4; ++i) {
                    const int ea = (rg * 16 + kq * 4 + i) * 264 + colb + cl;
                    float s = a2[i] + b2v;
                    float sig = 1.f / (1.f + __expf(-s));
                    xbf[ea] = f2bf(sig * bf2f(xbf[ea]));
                }
            }
        }
    }
    __syncthreads();
    // gelu(y' + res), coalesced store + stats (32 elements/thread)
    float ps[8] = {0, 0, 0, 0, 0, 0, 0, 0}, pq[8] = {0, 0, 0, 0, 0, 0, 0, 0};
#pragma unroll
    for (int it = 0; it < 4; ++it) {
        const int e = tid + it * 512;
        const int row = e >> 5, cb = (e & 31) * 8;
        const int grow = rowbase + row;
        if (grow < Mrows) {
            us8v xv = *(const us8v*)&xbf[row * 264 + cb];
            us8v rv = *(const us8v*)&Yout[((size_t)c * N_ + grow) * 256 + cb];
            us8v ov;
#pragma unroll
            for (int j = 0; j < 8; ++j) {
                float v = gelu_f(bf2f(xv[j]) + bf2f(rv[j]));
                ov[j] = f2bf(v);
                ps[j] += v;
                if (SMODE == 1) pq[j] += v * v;
            }
            *(us8v*)&Yout[((size_t)c * N_ + grow) * 256 + cb] = ov;
        }
    }
    __syncthreads();                 // xbf dead -> red may alias it
#pragma unroll
    for (int j = 0; j < 8; ++j)
        red[((tid >> 5) * 32 + (tid & 31)) * 8 + j] = ps[j];
    __syncthreads();
    if (tid < 256) {
        const int cb2 = tid >> 3, j2 = tid & 7;
        float s = 0.f;
#pragma unroll
        for (int r16 = 0; r16 < 16; ++r16) s += red[(r16 * 32 + cb2) * 8 + j2];
        atomicAdd(&ssum[c * 256 + cb2 * 8 + j2], s);
    }
    if (SMODE == 1) {
        __syncthreads();
#pragma unroll
        for (int j = 0; j < 8; ++j)
            red[((tid >> 5) * 32 + (tid & 31)) * 8 + j] = pq[j];
        __syncthreads();
        if (tid < 256) {
            const int cb2 = tid >> 3, j2 = tid & 7;
            float s = 0.f;
#pragma unroll
            for (int r16 = 0; r16 < 16; ++r16) s += red[(r16 * 32 + cb2) * 8 + j2];
            atomicAdd(&ssq[c * 256 + cb2 * 8 + j2], s);
        }
    }
}

// ---------------- fp32 tiled GEMM (one-time base GEMM) ----------------
__global__ __launch_bounds__(256) void gemm_k(const float* __restrict__ A1, int lda1,
                                              const float* __restrict__ W1, int K1,
                                              const float* __restrict__ bias,
                                              float* __restrict__ Y, int Mrows) {
    __shared__ float As[16][132];
    __shared__ float Bs[16][132];
    float acc[8][8];
#pragma unroll
    for (int i = 0; i < 8; ++i)
#pragma unroll
        for (int j = 0; j < 8; ++j) acc[i][j] = 0.f;

    const int tid = threadIdx.x;
    const int tr = tid >> 4, tc = tid & 15;
    const int rowbase = blockIdx.y * 128, colbase = blockIdx.x * 128;

    for (int k0 = 0; k0 < K1; k0 += 16) {
#pragma unroll
        for (int ii = 0; ii < 2; ++ii) {
            int i = tid + ii * 256;
            int rr = i >> 2, qq = i & 3;
            int grow = rowbase + rr;
            float4 vv = make_float4(0.f, 0.f, 0.f, 0.f);
            if (grow < Mrows) vv = *(const float4*)&A1[(size_t)grow * lda1 + k0 + qq * 4];
            As[qq * 4 + 0][rr] = vv.x;
            As[qq * 4 + 1][rr] = vv.y;
            As[qq * 4 + 2][rr] = vv.z;
            As[qq * 4 + 3][rr] = vv.w;
        }
#pragma unroll
        for (int ii = 0; ii < 2; ++ii) {
            int i = tid + ii * 256;
            int rr = i >> 5, qq = i & 31;
            float4 vv = *(const float4*)&W1[(size_t)(k0 + rr) * 256 + colbase + qq * 4];
            *(float4*)&Bs[rr][qq * 4] = vv;
        }
        __syncthreads();
#pragma unroll
        for (int kk = 0; kk < 16; ++kk) {
            float a[8], b[8];
            *(float4*)&a[0] = *(const float4*)&As[kk][tr * 4];
            *(float4*)&a[4] = *(const float4*)&As[kk][64 + tr * 4];
            *(float4*)&b[0] = *(const float4*)&Bs[kk][tc * 4];
            *(float4*)&b[4] = *(const float4*)&Bs[kk][64 + tc * 4];
#pragma unroll
            for (int i = 0; i < 8; ++i)
#pragma unroll
                for (int j = 0; j < 8; ++j)
                    acc[i][j] = fmaf(a[i], b[j], acc[i][j]);
        }
        __syncthreads();
    }

    float4 blo = *(const float4*)&bias[colbase + tc * 4];
    float4 bhi = *(const float4*)&bias[colbase + 64 + tc * 4];
    float bb[8] = {blo.x, blo.y, blo.z, blo.w, bhi.x, bhi.y, bhi.z, bhi.w};
#pragma unroll
    for (int i = 0; i < 8; ++i)
#pragma unroll
        for (int j = 0; j < 8; ++j) acc[i][j] += bb[j];

#pragma unroll
    for (int i = 0; i < 8; ++i) {
        int lrow = (i < 4) ? (tr * 4 + i) : (64 + tr * 4 + (i - 4));
        int grow = rowbase + lrow;
        if (grow < Mrows) {
            *(float4*)&Y[(size_t)grow * 256 + colbase + tc * 4] =
                make_float4(acc[i][0], acc[i][1], acc[i][2], acc[i][3]);
            *(float4*)&Y[(size_t)grow * 256 + colbase + 64 + tc * 4] =
                make_float4(acc[i][4], acc[i][5], acc[i][6], acc[i][7]);
        }
    }
}

// ---------------- per-row epilogue with MFMA channel-attention (512 thr, 8 waves) ----------------
// norm stats computed inline from nssum/nssq (finstat removed)
template <int NORM, int RES, int SMODE>
__global__ __launch_bounds__(512) void apply_k(const u16* __restrict__ Yin,
                                               u16* __restrict__ Hout,
                                               const u16* __restrict__ Hsc,
                                               const u16* __restrict__ W1p,
                                               const float* __restrict__ b1,
                                               const u16* __restrict__ W2p,
                                               const float* __restrict__ b2,
                                               const float* __restrict__ nssum,
                                               const float* __restrict__ nssq,
                                               float* __restrict__ ssum,
                                               float* __restrict__ ssq) {
    __shared__ u16 vbf[16 * 264];
    __shared__ u16 scs[(RES ? 16 : 1) * 264];
    __shared__ float tpart[8 * 528];
    __shared__ u16 tbf[16 * 40];
    __shared__ float srs[NORM ? 256 : 1], smrs[NORM ? 256 : 1];
    const int c = blockIdx.z, n0 = blockIdx.x * 16, tid = threadIdx.x;
    const int lane = tid & 63, wid = tid >> 6;   // wid 0..7
    const size_t rowbase = ((size_t)c * N_ + n0) * 256;

    if (NORM && tid < 256) {
        float m = nssum[c * 256 + tid] * (1.0f / (float)N_);
        float v = nssq[c * 256 + tid] * (1.0f / (float)N_) - m * m;
        float r = rsqrtf(v + EPS_);
        srs[tid] = r;
        smrs[tid] = m * r;
    }
    {
        const int row = tid >> 5, cb = (tid & 31) * 8;
        us8v x = *(const us8v*)&Yin[rowbase + row * 256 + cb];
        us8v r;
        if (RES) r = *(const us8v*)&Hsc[rowbase + row * 256 + cb];
        if (NORM) {
            __syncthreads();
            us8v y;
#pragma unroll
            for (int j = 0; j < 8; ++j)
                y[j] = f2bf(fmaf(bf2f(x[j]), srs[cb + j], -smrs[cb + j]));
            *(us8v*)&vbf[row * 264 + cb] = y;
        } else {
            *(us8v*)&vbf[row * 264 + cb] = x;
        }
        if (RES) *(us8v*)&scs[row * 264 + cb] = r;
    }
    __syncthreads();

    {
        const int arow = lane & 15, kq = lane >> 4;
        const int k = wid * 32 + kq * 8;
        s16x8 aF = *(const s16x8*)&vbf[arow * 264 + k];
        s16x8 bF0 = *(const s16x8*)&W1p[((wid * 2 + 0) * 64 + lane) * 8];
        s16x8 bF1 = *(const s16x8*)&W1p[((wid * 2 + 1) * 64 + lane) * 8];
        f32x4 at0 = __builtin_amdgcn_mfma_f32_16x16x32_bf16(aF, bF0, (f32x4)0.f, 0, 0, 0);
        f32x4 at1 = __builtin_amdgcn_mfma_f32_16x16x32_bf16(aF, bF1, (f32x4)0.f, 0, 0, 0);
#pragma unroll
        for (int i = 0; i < 4; ++i) {
            tpart[wid * 528 + (kq * 4 + i) * 33 + (lane & 15)] = at0[i];
            tpart[wid * 528 + (kq * 4 + i) * 33 + 16 + (lane & 15)] = at1[i];
        }
    }
    __syncthreads();

    {
        const int nr = tid >> 5, col = tid & 31;
        float s = b1[col];
#pragma unroll
        for (int w8 = 0; w8 < 8; ++w8)
            s += tpart[w8 * 528 + nr * 33 + col];
        tbf[nr * 40 + col] = f2bf(fmaxf(s, 0.f));
    }
    __syncthreads();

    {
        const int cl = lane & 15, kq = lane >> 4;
        s16x8 aF = *(const s16x8*)&tbf[cl * 40 + kq * 8];
        float ps[2] = {0, 0}, pq[2] = {0, 0};
#pragma unroll
        for (int q = 0; q < 2; ++q) {
            const int colb = (wid * 2 + q) * 16;
            s16x8 bF = *(const s16x8*)&W2p[((wid * 2 + q) * 64 + lane) * 8];
            f32x4 acc = __builtin_amdgcn_mfma_f32_16x16x32_bf16(aF, bF, (f32x4)0.f, 0, 0, 0);
            const float b2v = b2[colb + cl];
#pragma unroll
            for (int i = 0; i < 4; ++i) {
                const int row = kq * 4 + i;
                const int ea = row * 264 + colb + cl;
                float s = acc[i] + b2v;
                float sig = 1.0f / (1.0f + __expf(-s));
                float val = sig * bf2f(vbf[ea]);
                if (RES) val += bf2f(scs[ea]);
                val = gelu_f(val);
                vbf[ea] = f2bf(val);
                if (SMODE) { ps[q] += val; if (SMODE == 1) pq[q] += val * val; }
            }
        }
        if (SMODE) {
#pragma unroll
            for (int q = 0; q < 2; ++q) {
                float s = ps[q];
                s += __shfl_xor(s, 16); s += __shfl_xor(s, 32);
                if (SMODE == 1) {
                    float q2 = pq[q];
                    q2 += __shfl_xor(q2, 16); q2 += __shfl_xor(q2, 32);
                    if (lane < 16) atomicAdd(&ssq[c * 256 + (wid * 2 + q) * 16 + lane], q2);
                }
                if (lane < 16) atomicAdd(&ssum[c * 256 + (wid * 2 + q) * 16 + lane], s);
            }
        }
    }
    __syncthreads();

    {
        const int row = tid >> 5, cb = (tid & 31) * 8;
        us8v h = *(const us8v*)&vbf[row * 264 + cb];
        *(us8v*)&Hout[rowbase + row * 256 + cb] = h;
    }
}

// ---------------- classifier ----------------
__global__ __launch_bounds__(256) void cls_k(const float* __restrict__ pooled_sum,
                                             const float* __restrict__ clsW,
                                             const float* __restrict__ clsb,
                                             float* __restrict__ out) {
    __shared__ float red[256];
    int c = blockIdx.x, d = threadIdx.x;
    red[d] = pooled_sum[c * 256 + d] * (1.0f / (float)N_) * clsW[d];
    __syncthreads();
    for (int s = 128; s > 0; s >>= 1) {
        if (d < s) red[d] += red[d + s];
        __syncthreads();
    }
    if (d == 0) out[c] = red[0] + clsb[0];
}

// ---------------- host launch ----------------
static inline size_t alup(size_t x) { return (x + 255) & ~(size_t)255; }

extern "C" void kernel_launch(void* const* d_in, const int* in_sizes, int n_in,
                              void* d_out, int out_size, void* d_ws, size_t ws_size,
                              hipStream_t stream) {
    const int*   xcfg   = (const int*)d_in[0];
    const float* xfeat  = (const float*)d_in[1];
    const int*   xlay   = (const int*)d_in[2];
    const int*   xop    = (const int*)d_in[3];
    const int*   ei     = (const int*)d_in[4];
    const int*   ncid   = (const int*)d_in[5];
    const float* embO   = (const float*)d_in[6];
    const float* embL   = (const float*)d_in[7];
    const float* lin1W  = (const float*)d_in[8];
    const float* lin1b  = (const float*)d_in[9];
    const float* ca1W1  = (const float*)d_in[10];
    const float* ca1b1  = (const float*)d_in[11];
    const float* ca1W2  = (const float*)d_in[12];
    const float* ca1b2  = (const float*)d_in[13];
    const float* lin2W  = (const float*)d_in[14];
    const float* lin2b  = (const float*)d_in[15];
    const float* ca2W1  = (const float*)d_in[16];
    const float* ca2b1  = (const float*)d_in[17];
    const float* ca2W2  = (const float*)d_in[18];
    const float* ca2b2  = (const float*)d_in[19];
    const float* sageWl = (const float*)d_in[20];
    const float* sagebl = (const float*)d_in[21];
    const float* sageWr = (const float*)d_in[22];
    const float* scaW1  = (const float*)d_in[23];
    const float* scab1  = (const float*)d_in[24];
    const float* scaW2  = (const float*)d_in[25];
    const float* scab2  = (const float*)d_in[26];
    const float* clsW   = (const float*)d_in[27];
    const float* clsb   = (const float*)d_in[28];
    float* out = (float*)d_out;

    // ---- workspace carve-up ----
    char* w = (char*)d_ws;
    size_t o = 0;
    auto take = [&](size_t bytes) { char* p = w + o; o = alup(o + bytes); return p; };
    float* base    = (float*)take((size_t)N_ * 256 * 4);
    float* feat162 = (float*)take((size_t)N_ * 176 * 4);
    float* W162    = (float*)take((size_t)176 * 256 * 4);
    float* T       = (float*)take((size_t)18 * 8 * 256 * 4);
    float* csum    = (float*)take((size_t)256 * 4);
    float* stats   = (float*)take((size_t)6 * 8192 * 4);
    float* invcnt  = (float*)take((size_t)N_ * 4);
    int*   cnt     = (int*)take((size_t)N_ * 4);
    int*   off     = (int*)take((size_t)(N_ + 1) * 4);
    int*   cursor  = (int*)take((size_t)N_ * 4);
    int*   csr     = (int*)take((size_t)E_ * 4);
    int*   cfgpos  = (int*)take((size_t)N_ * 4);
    u16*   Wt2     = (u16*)take((size_t)256 * 256 * 2);
    u16*   Wfold   = (u16*)take((size_t)C_ * 256 * 512 * 2);   // 4 MB
    float* biasF   = (float*)take((size_t)C_ * 256 * 4);
    u16*   CAW1    = (u16*)take((size_t)5 * 8192 * 2);         // packed frag order
    u16*   CAW2    = (u16*)take((size_t)5 * 8192 * 2);

    const size_t slab = (size_t)SZ_ * 2;                       // bf16: 5.12 MB
    size_t avail = (ws_size > o) ? (ws_size - o) : 0;
    int Cc = (int)(avail / (3 * slab + 768));
    if (Cc > C_) Cc = C_;
    if (Cc < 1) Cc = 1;
    u16* BufH = (u16*)take((size_t)Cc * slab);
    u16* BufY = (u16*)take((size_t)Cc * slab);
    u16* BufA = (u16*)take((size_t)Cc * slab);
    (void)in_sizes; (void)n_in; (void)out_size;

    auto S = [&](int s) { return stats + (size_t)s * 8192; };
    auto Q = [&](int s) { return stats + (size_t)s * 8192 + 4096; };

    hipMemsetAsync(stats, 0, 6 * 8192 * 4, stream);
    hipMemsetAsync(cnt, 0, N_ * 4, stream);
    hipMemsetAsync(cfgpos, 0xFF, N_ * 4, stream);

    // shared prep
    tbl_k<<<144, 256, 0, stream>>>(embL, lin1W, T);
    csum_k<<<1, 256, 0, stream>>>(T, csum);
    feat_k<<<N_, 192, 0, stream>>>(xfeat, xlay, xop, embL, embO, feat162);
    wpack_k<<<176, 256, 0, stream>>>(lin1W, W162);
    wt2_k<<<256, 256, 0, stream>>>(lin2W, Wt2);
    packw1_k<<<32, 256, 0, stream>>>(ca1W1, CAW1 + 0 * 8192);
    packw1_k<<<32, 256, 0, stream>>>(ca2W1, CAW1 + 1 * 8192);
    packw1_k<<<32, 256, 0, stream>>>(scaW1 + 0 * 8192, CAW1 + 2 * 8192);
    packw1_k<<<32, 256, 0, stream>>>(scaW1 + 1 * 8192, CAW1 + 3 * 8192);
    packw1_k<<<32, 256, 0, stream>>>(scaW1 + 2 * 8192, CAW1 + 4 * 8192);
    packw2_k<<<32, 256, 0, stream>>>(ca1W2, CAW2 + 0 * 8192);
    packw2_k<<<32, 256, 0, stream>>>(ca2W2, CAW2 + 1 * 8192);
    packw2_k<<<32, 256, 0, stream>>>(scaW2 + 0 * 8192, CAW2 + 2 * 8192);
    packw2_k<<<32, 256, 0, stream>>>(scaW2 + 1 * 8192, CAW2 + 3 * 8192);
    packw2_k<<<32, 256, 0, stream>>>(scaW2 + 2 * 8192, CAW2 + 4 * 8192);
    cfgpos_k<<<(NC_ + 255) / 256, 256, 0, stream>>>(ncid, cfgpos);
    hist_k<<<(E_ + 255) / 256, 256, 0, stream>>>(ei, cnt);
    scan_k<<<1, 1024, 0, stream>>>(cnt, off, cursor, invcnt);
    fill_k<<<(E_ + 255) / 256, 256, 0, stream>>>(ei, cursor, csr);

    // base = feat162 @ W162 + lin1_b (fp32, one-time)
    gemm_k<<<dim3(2, 79, 1), 256, 0, stream>>>(feat162, 176, W162, 176, lin1b, base, N_);

    // ---- per-config-chunk pipeline ----
    for (int c0 = 0; c0 < C_; c0 += Cc) {
        const int nc = (C_ - c0 < Cc) ? (C_ - c0) : Cc;
        const int co = c0 * 256;

        lin1_cfg_k<<<dim3(NC_ / 16, 1, nc), 256, 0, stream>>>(
            base, T, ncid, xcfg + (size_t)c0 * NC_ * 18, BufH, S(0) + co, Q(0) + co);
        lin1_unc_k<<<625, 256, 0, stream>>>(
            base, csum, cfgpos, nc, BufH, S(0) + co, Q(0) + co);

        apply_k<1, 0, 0><<<dim3(625, 1, nc), 512, 0, stream>>>(
            BufH, BufH, nullptr, CAW1 + 0 * 8192, ca1b1, CAW2 + 0 * 8192, ca1b2,
            S(0) + co, Q(0) + co, nullptr, nullptr);

        mgemm_k<1><<<dim3(2, 79, nc), 256, 0, stream>>>(
            BufH, SZ_, nullptr, 0, Wt2, 0, 256, 256,
            lin2b, 0, BufY, SZ_, N_, S(1) + co, Q(1) + co);

        apply_k<1, 0, 1><<<dim3(625, 1, nc), 512, 0, stream>>>(
            BufY, BufY, nullptr, CAW1 + 1 * 8192, ca2b1, CAW2 + 1 * 8192, ca2b2,
            S(1) + co, Q(1) + co, S(2) + co, Q(2) + co);

        for (int i = 0; i < 3; ++i) {
            const int set = 2 + i;
            foldw_k<<<dim3(256, nc), 256, 0, stream>>>(
                sageWl + (size_t)i * 65536, sageWr + (size_t)i * 65536, sagebl + i * 256,
                S(set) + co, Q(set) + co,
                Wfold + (size_t)c0 * 256 * 512, biasF + co);
            agg_k<<<nc * 2500, 256, 0, stream>>>(BufY, off, csr, invcnt,
                                                 S(set) + co, BufA);
            if (i < 2) {
                msage_k<1><<<dim3(157, nc), 512, 0, stream>>>(
                    BufA, BufY, Wfold + (size_t)c0 * 256 * 512, 256 * 512, biasF + co,
                    CAW1 + (2 + i) * 8192, scab1 + i * 32,
                    CAW2 + (2 + i) * 8192, scab2 + i * 256,
                    BufY, N_, S(3 + i) + co, Q(3 + i) + co);
            } else {
                msage_k<2><<<dim3(157, nc), 512, 0, stream>>>(
                    BufA, BufY, Wfold + (size_t)c0 * 256 * 512, 256 * 512, biasF + co,
                    CAW1 + (2 + i) * 8192, scab1 + i * 32,
                    CAW2 + (2 + i) * 8192, scab2 + i * 256,
                    BufY, N_, S(5) + co, nullptr);
            }
        }
    }

    cls_k<<<16, 256, 0, stream>>>(S(5), clsW, clsb, out);
}

// Round 19
// 1129.941 us; speedup vs baseline: 1.0234x; 1.0204x over previous
//
#include <hip/hip_runtime.h>
#include <hip/hip_bf16.h>
#include <math.h>

// ---------------- problem constants ----------------
constexpr int C_  = 16;
constexpr int N_  = 10000;
constexpr int NC_ = 2000;
constexpr int E_  = 50000;
constexpr int D_  = 256;
constexpr int SZ_ = N_ * D_;          // per-config slab (elements)
constexpr float EPS_ = 1e-5f;

typedef unsigned short u16;
typedef __attribute__((ext_vector_type(8))) unsigned short us8v;
typedef __attribute__((ext_vector_type(4))) unsigned short us4v;
typedef __attribute__((ext_vector_type(8))) short s16x8;
typedef __attribute__((ext_vector_type(4))) float f32x4;

typedef __attribute__((address_space(3))) unsigned int lds_uint;
typedef const __attribute__((address_space(1))) unsigned int glb_uint;

__device__ __forceinline__ u16 f2bf(float f) {
    __hip_bfloat16 h = __float2bfloat16(f);   // hw v_cvt (RNE)
    return __builtin_bit_cast(u16, h);
}
__device__ __forceinline__ float bf2f(u16 h) {
    return __uint_as_float(((unsigned)h) << 16);
}
// fast gelu: erf via Abramowitz-Stegun 7.1.26 (|err|<=1.5e-7) + hw exp
__device__ __forceinline__ float gelu_f(float x) {
    float z = x * 0.70710678118654752f;
    float az = fabsf(z);
    float t = 1.f / fmaf(0.3275911f, az, 1.f);
    float p = t * (0.254829592f + t * (-0.284496736f + t * (1.421413741f +
              t * (-1.453152027f + t * 1.061405429f))));
    float e = p * __expf(-z * z);
    float erfv = (z >= 0.f) ? (1.f - e) : (e - 1.f);
    return 0.5f * x * (1.f + erfv);
}

// ---------------- tiny prep kernels ----------------

__global__ __launch_bounds__(256) void tbl_k(const float* __restrict__ embL,
                                             const float* __restrict__ W,
                                             float* __restrict__ T) {
    int b = blockIdx.x;            // 0..143
    int s = b >> 3, i = b & 7, d = threadIdx.x;
    float acc = 0.f;
#pragma unroll
    for (int k = 0; k < 4; ++k)
        acc = fmaf(embL[i * 4 + k], W[(134 + s * 4 + k) * 256 + d], acc);
    T[(s * 8 + i) * 256 + d] = acc;
}

// csum[d] = sum_s T[s][0][d]
__global__ __launch_bounds__(256) void csum_k(const float* __restrict__ T,
                                              float* __restrict__ cs) {
    int d = threadIdx.x;
    float a = 0.f;
#pragma unroll
    for (int s = 0; s < 18; ++s) a += T[(s * 8) * 256 + d];
    cs[d] = a;
}

__global__ __launch_bounds__(192) void feat_k(const float* __restrict__ xf,
                                              const int* __restrict__ xlay,
                                              const int* __restrict__ xop,
                                              const float* __restrict__ embL,
                                              const float* __restrict__ embO,
                                              float* __restrict__ f) {
    int n = blockIdx.x, j = threadIdx.x;
    if (j >= 176) return;
    float v;
    if (j < 134) v = xf[n * 134 + j];
    else if (j < 158) { int q = j - 134; int t = q >> 2, k = q & 3; v = embL[(xlay[n * 6 + t] + 2) * 4 + k]; }
    else if (j < 162) { int k = j - 158; v = embO[xop[n] * 4 + k]; }
    else v = 0.f;
    f[n * 176 + j] = v;
}

__global__ __launch_bounds__(256) void wpack_k(const float* __restrict__ W,
                                               float* __restrict__ Wp) {
    int j = blockIdx.x, d = threadIdx.x;
    float v = 0.f;
    if (j < 134) v = W[j * 256 + d];
    else if (j < 158) v = W[(206 + j - 134) * 256 + d];
    else if (j < 162) v = W[(230 + j - 158) * 256 + d];
    Wp[j * 256 + d] = v;
}

// pack channel-attn W1 [256][32] into MFMA fragment order
__global__ __launch_bounds__(256) void packw1_k(const float* __restrict__ W1,
                                                u16* __restrict__ dst) {
    int i = blockIdx.x * 256 + threadIdx.x;    // 0..8191
    int j = i & 7, lane = (i >> 3) & 63, half = (i >> 9) & 1, ks = (i >> 10) & 1, wid = (i >> 11) & 3;
    int k = wid * 64 + ks * 32 + ((lane >> 4) << 3) + j;
    int col = half * 16 + (lane & 15);
    dst[i] = f2bf(W1[k * 32 + col]);
}
// pack channel-attn W2 [32][256] into MFMA fragment order
__global__ __launch_bounds__(256) void packw2_k(const float* __restrict__ W2,
                                                u16* __restrict__ dst) {
    int i = blockIdx.x * 256 + threadIdx.x;    // 0..8191
    int j = i & 7, lane = (i >> 3) & 63, q = (i >> 9) & 3, wid = (i >> 11) & 3;
    int kq = lane >> 4, cl = lane & 15;
    dst[i] = f2bf(W2[(kq * 8 + j) * 256 + (wid * 4 + q) * 16 + cl]);
}

__global__ __launch_bounds__(256) void cfgpos_k(const int* __restrict__ ncid,
                                                int* __restrict__ cfgpos) {
    int i = blockIdx.x * 256 + threadIdx.x;
    if (i < NC_) cfgpos[ncid[i]] = i;
}

__global__ __launch_bounds__(256) void hist_k(const int* __restrict__ ei, int* __restrict__ cnt) {
    int e = blockIdx.x * 256 + threadIdx.x;
    if (e < E_) atomicAdd(&cnt[ei[E_ + e]], 1);
}

__global__ __launch_bounds__(1024) void scan_k(const int* __restrict__ cnt,
                                               int* __restrict__ off,
                                               int* __restrict__ cursor,
                                               float* __restrict__ invcnt) {
    __shared__ int s[1024];
    int t = threadIdx.x;
    int base = t * 10;
    int local[10];
    int part = 0;
#pragma unroll
    for (int k = 0; k < 10; ++k) {
        int idx = base + k;
        int v = (idx < N_) ? cnt[idx] : 0;
        local[k] = v; part += v;
    }
    s[t] = part;
    __syncthreads();
    for (int o = 1; o < 1024; o <<= 1) {
        int val = (t >= o) ? s[t - o] : 0;
        __syncthreads();
        s[t] += val;
        __syncthreads();
    }
    int pre = s[t] - part;
#pragma unroll
    for (int k = 0; k < 10; ++k) {
        int idx = base + k;
        if (idx < N_) {
            off[idx] = pre;
            cursor[idx] = pre;
            invcnt[idx] = 1.0f / (float)(local[k] > 1 ? local[k] : 1);
            pre += local[k];
        }
    }
    if (t == 1023) off[N_] = s[1023];
}

__global__ __launch_bounds__(256) void fill_k(const int* __restrict__ ei,
                                              int* __restrict__ cursor,
                                              int* __restrict__ csr) {
    int e = blockIdx.x * 256 + threadIdx.x;
    if (e < E_) {
        int t = ei[E_ + e];
        int p = atomicAdd(&cursor[t], 1);
        csr[p] = ei[e];
    }
}

// transpose lin2_W -> Wt2[j][k] bf16
__global__ __launch_bounds__(256) void wt2_k(const float* __restrict__ W,
                                             u16* __restrict__ Wt) {
    int j = blockIdx.x, k = threadIdx.x;
    Wt[j * 256 + k] = f2bf(W[k * 256 + j]);
}

// fold instance-norm into sage weights (per config); stats computed inline
__global__ __launch_bounds__(256) void foldw_k(const float* __restrict__ Wl,
                                               const float* __restrict__ Wr,
                                               const float* __restrict__ bl,
                                               const float* __restrict__ nssum,
                                               const float* __restrict__ nssq,
                                               u16* __restrict__ Wt,
                                               float* __restrict__ biasF) {
    __shared__ float red[256];
    int c = blockIdx.y, j = blockIdx.x, k = threadIdx.x;
    float m = nssum[c * 256 + k] * (1.0f / (float)N_);
    float v = nssq[c * 256 + k] * (1.0f / (float)N_) - m * m;
    float rsv = rsqrtf(v + EPS_);
    float muv = m;
    float fl = rsv * Wl[k * 256 + j];
    float fr = rsv * Wr[k * 256 + j];
    size_t wb = ((size_t)c * 256 + j) * 512;
    Wt[wb + k] = f2bf(fl);
    Wt[wb + 256 + k] = f2bf(fr);
    red[k] = muv * (fl + fr);
    __syncthreads();
    for (int s = 128; s > 0; s >>= 1) {
        if (k < s) red[k] += red[k + s];
        __syncthreads();
    }
    if (k == 0) biasF[c * 256 + j] = bl[j] - red[0];
}

// ---------------- lin1 (configured nodes) ----------------
__global__ __launch_bounds__(256) void lin1_cfg_k(const float* __restrict__ base,
                                                  const float* __restrict__ T,
                                                  const int* __restrict__ ncid,
                                                  const int* __restrict__ xcfg,
                                                  u16* __restrict__ H,
                                                  float* __restrict__ ssum,
                                                  float* __restrict__ ssq) {
    __shared__ int idxs[16][18];   // premultiplied by 256
    __shared__ int nid[16];
    const int c = blockIdx.z, j0 = blockIdx.x * 16, tid = threadIdx.x;
    if (tid < 16) nid[tid] = ncid[j0 + tid];
    for (int t = tid; t < 288; t += 256) {
        int row = t / 18, s = t - row * 18;
        idxs[row][s] = (xcfg[((size_t)c * NC_ + j0 + row) * 18 + s] + 2) * 256;
    }
    __syncthreads();
    const int d = tid;
    float psum = 0.f, psq = 0.f;
    for (int g = 0; g < 16; g += 4) {
        float acc[4];
#pragma unroll
        for (int gg = 0; gg < 4; ++gg) acc[gg] = base[(size_t)nid[g + gg] * 256 + d];
#pragma unroll
        for (int s = 0; s < 18; ++s) {
            const float* Ts = &T[s * 2048 + d];
#pragma unroll
            for (int gg = 0; gg < 4; ++gg)
                acc[gg] += Ts[idxs[g + gg][s]];
        }
#pragma unroll
        for (int gg = 0; gg < 4; ++gg) {
            H[((size_t)c * N_ + nid[g + gg]) * 256 + d] = f2bf(acc[gg]);
            psum += acc[gg]; psq += acc[gg] * acc[gg];
        }
    }
    atomicAdd(&ssum[c * 256 + d], psum);
    atomicAdd(&ssq[c * 256 + d], psq);
}

// ---------------- lin1 (unconfigured nodes) ----------------
__global__ __launch_bounds__(256) void lin1_unc_k(const float* __restrict__ base,
                                                  const float* __restrict__ csum,
                                                  const int* __restrict__ cfgpos,
                                                  int nc,
                                                  u16* __restrict__ H,
                                                  float* __restrict__ ssum,
                                                  float* __restrict__ ssq) {
    __shared__ float red[2048];
    const int n0 = blockIdx.x * 16, tid = threadIdx.x;
    float ps[8] = {0, 0, 0, 0, 0, 0, 0, 0}, pq[8] = {0, 0, 0, 0, 0, 0, 0, 0};
#pragma unroll
    for (int it = 0; it < 2; ++it) {
        const int flat = tid + it * 256;
        const int row = flat >> 5, cb = (flat & 31) * 8;
        const int n = n0 + row;
        if (cfgpos[n] >= 0) continue;
        us8v b;
#pragma unroll
        for (int j = 0; j < 8; ++j) {
            float v = base[(size_t)n * 256 + cb + j] + csum[cb + j];
            b[j] = f2bf(v);
            ps[j] += v; pq[j] += v * v;
        }
        for (int c = 0; c < nc; ++c)
            *(us8v*)&H[((size_t)c * N_ + n) * 256 + cb] = b;
    }
#pragma unroll
    for (int j = 0; j < 8; ++j)
        red[((tid >> 5) * 32 + (tid & 31)) * 8 + j] = ps[j];
    __syncthreads();
    {
        const int cb2 = tid >> 3, j2 = tid & 7;
        float s = 0.f;
#pragma unroll
        for (int r8 = 0; r8 < 8; ++r8) s += red[(r8 * 32 + cb2) * 8 + j2];
        for (int c = 0; c < nc; ++c) atomicAdd(&ssum[c * 256 + tid], s);
    }
    __syncthreads();
#pragma unroll
    for (int j = 0; j < 8; ++j)
        red[((tid >> 5) * 32 + (tid & 31)) * 8 + j] = pq[j];
    __syncthreads();
    {
        const int cb2 = tid >> 3, j2 = tid & 7;
        float s = 0.f;
#pragma unroll
        for (int r8 = 0; r8 < 8; ++r8) s += red[(r8 * 32 + cb2) * 8 + j2];
        for (int c = 0; c < nc; ++c) atomicAdd(&ssq[c * 256 + tid], s);
    }
}

// ---------------- CSR gather-mean: vector index load + shfl broadcast ----------------
// deg-0 rows write mu computed inline from ssum
__global__ __launch_bounds__(256) void agg_k(const u16* __restrict__ H,
                                             const int* __restrict__ off,
                                             const int* __restrict__ csr,
                                             const float* __restrict__ invcnt,
                                             const float* __restrict__ nssum,
                                             u16* __restrict__ Agg) {
    int wave = threadIdx.x >> 6, lane = threadIdx.x & 63;
    int pair = blockIdx.x * 4 + wave;
    int c = pair / N_, t = pair - c * N_;
    int d4 = lane * 4;
    int o0 = off[t], o1 = off[t + 1];
    int deg = o1 - o0;
    us4v o;
    if (deg > 0) {
        int myidx = (lane < deg) ? csr[o0 + lane] : 0;
        const u16* Hc = H + (size_t)c * SZ_ + d4;
        float ax = 0.f, ay = 0.f, az = 0.f, aw = 0.f;
        int lim = deg < 64 ? deg : 64;
        int i = 0;
        for (; i + 4 <= lim; i += 4) {
            int s0 = __shfl(myidx, i), s1 = __shfl(myidx, i + 1);
            int s2 = __shfl(myidx, i + 2), s3 = __shfl(myidx, i + 3);
            us4v h0 = *(const us4v*)&Hc[(size_t)s0 * 256];
            us4v h1 = *(const us4v*)&Hc[(size_t)s1 * 256];
            us4v h2 = *(const us4v*)&Hc[(size_t)s2 * 256];
            us4v h3 = *(const us4v*)&Hc[(size_t)s3 * 256];
            ax += (bf2f(h0.x) + bf2f(h1.x)) + (bf2f(h2.x) + bf2f(h3.x));
            ay += (bf2f(h0.y) + bf2f(h1.y)) + (bf2f(h2.y) + bf2f(h3.y));
            az += (bf2f(h0.z) + bf2f(h1.z)) + (bf2f(h2.z) + bf2f(h3.z));
            aw += (bf2f(h0.w) + bf2f(h1.w)) + (bf2f(h2.w) + bf2f(h3.w));
        }
        for (; i < lim; ++i) {
            int s = __shfl(myidx, i);
            us4v h = *(const us4v*)&Hc[(size_t)s * 256];
            ax += bf2f(h.x); ay += bf2f(h.y); az += bf2f(h.z); aw += bf2f(h.w);
        }
        for (int j = o0 + 64; j < o1; ++j) {     // rare: degree > 64
            int s = csr[j];
            us4v h = *(const us4v*)&Hc[(size_t)s * 256];
            ax += bf2f(h.x); ay += bf2f(h.y); az += bf2f(h.z); aw += bf2f(h.w);
        }
        float inv = invcnt[t];
        o.x = f2bf(ax * inv); o.y = f2bf(ay * inv);
        o.z = f2bf(az * inv); o.w = f2bf(aw * inv);
    } else {
        const float invN = 1.0f / (float)N_;
        o.x = f2bf(nssum[c * 256 + d4 + 0] * invN);
        o.y = f2bf(nssum[c * 256 + d4 + 1] * invN);
        o.z = f2bf(nssum[c * 256 + d4 + 2] * invN);
        o.w = f2bf(nssum[c * 256 + d4 + 3] * invN);
    }
    *(us4v*)&Agg[((size_t)c * N_ + t) * 256 + d4] = o;
}

// ---------------- bf16 MFMA GEMM (128x128 tile, 2-phase dbuf): Y = [A1|A2] @ Wt^T + bias ----------------
template <int STATS>
__global__ __launch_bounds__(256) void mgemm_k(
    const u16* __restrict__ A1, size_t sA1,
    const u16* __restrict__ A2, size_t sA2,
    const u16* __restrict__ Wt, size_t sW, int K1, int Ktot,
    const float* __restrict__ bias, size_t sBias,
    u16* __restrict__ Y, size_t sY, int Mrows,
    float* __restrict__ ssum, float* __restrict__ ssq)
{
    __shared__ __align__(16) char SM[65536];   // 2 x (A 16KB + B 16KB)
    const int tid = threadIdx.x;
    const int lane = tid & 63, wid = tid >> 6;
    const int wr = wid >> 1, wc = wid & 1;

    // XCD-aware bijective remap of the flattened block id
    const int gx = gridDim.x, gy = gridDim.y;
    int nwg = gx * gy * gridDim.z;
    int orig = blockIdx.x + gx * (blockIdx.y + gy * blockIdx.z);
    int q = nwg >> 3, r = nwg & 7;
    int xcd = orig & 7, idx = orig >> 3;
    int swz = (xcd < r ? xcd * (q + 1) : r * (q + 1) + (xcd - r) * q) + idx;
    const int bx = swz % gx;
    const int tmp = swz / gx;
    const int by = tmp % gy;
    const int c  = tmp / gy;

    const int rowbase = by * 128, colbase = bx * 128;

    const u16* A1p = A1 + (size_t)c * sA1;
    const u16* A2p = A2 ? (A2 + (size_t)c * sA2) : nullptr;
    const u16* Wp  = Wt + (size_t)c * sW;

    f32x4 acc[4][4];
#pragma unroll
    for (int i = 0; i < 4; ++i)
#pragma unroll
        for (int j = 0; j < 4; ++j) acc[i][j] = (f32x4)0.f;

    auto stage = [&](int buf, int k0) {
        const u16* asrc; int ak;
        if (k0 < K1) { asrc = A1p; ak = k0; } else { asrc = A2p; ak = k0 - K1; }
        u16* Ab = (u16*)(SM + buf * 32768);
        u16* Bb = (u16*)(SM + buf * 32768 + 16384);
#pragma unroll
        for (int jj = 0; jj < 4; ++jj) {
            const int u = tid + jj * 256;
            const int row = u >> 3, chunk = u & 7;
            const int sc2 = chunk ^ (row & 7);
            int garow = rowbase + row;
            if (garow >= Mrows) garow = Mrows - 1;             // clamp: values unused
            __builtin_amdgcn_global_load_lds(
                (glb_uint*)(asrc + (size_t)garow * 256 + ak + sc2 * 8),
                (lds_uint*)(Ab + u * 8), 16, 0, 0);
            __builtin_amdgcn_global_load_lds(
                (glb_uint*)(Wp + (size_t)(colbase + row) * Ktot + k0 + sc2 * 8),
                (lds_uint*)(Bb + u * 8), 16, 0, 0);
        }
    };

    const int nsteps = Ktot >> 6;
    stage(0, 0);
    __syncthreads();                 // drain prologue (implicit vmcnt(0))
    int cur = 0;
    for (int t = 0; t < nsteps; ++t) {
        if (t + 1 < nsteps) stage(cur ^ 1, (t + 1) * 64);   // overlap with MFMA
        const u16* Asm = (const u16*)(SM + cur * 32768);
        const u16* Bsm = (const u16*)(SM + cur * 32768 + 16384);
#pragma unroll
        for (int ks = 0; ks < 2; ++ks) {
            s16x8 aF[4], bF[4];
            const int kk = ks * 32 + ((lane >> 4) << 3);
#pragma unroll
            for (int f = 0; f < 4; ++f) {
                int ar = wr * 64 + f * 16 + (lane & 15);
                aF[f] = *(const s16x8*)&Asm[(ar * 64 + kk) ^ ((ar & 7) << 3)];
                int br = wc * 64 + f * 16 + (lane & 15);
                bF[f] = *(const s16x8*)&Bsm[(br * 64 + kk) ^ ((br & 7) << 3)];
            }
#pragma unroll
            for (int fr = 0; fr < 4; ++fr)
#pragma unroll
                for (int fc = 0; fc < 4; ++fc)
                    acc[fr][fc] = __builtin_amdgcn_mfma_f32_16x16x32_bf16(
                        aF[fr], bF[fc], acc[fr][fc], 0, 0, 0);
        }
        __syncthreads();             // next buf staged, cur reads done
        cur ^= 1;
    }

    float bcol[4];
#pragma unroll
    for (int fc = 0; fc < 4; ++fc)
        bcol[fc] = bias[(size_t)c * sBias + colbase + wc * 64 + fc * 16 + (lane & 15)];
    u16* Yp = Y + (size_t)c * sY;
    float ps[4] = {0, 0, 0, 0}, pq[4] = {0, 0, 0, 0};
#pragma unroll
    for (int fr = 0; fr < 4; ++fr) {
#pragma unroll
        for (int i = 0; i < 4; ++i) {
            int grow = rowbase + wr * 64 + fr * 16 + ((lane >> 4) << 2) + i;
            if (grow < Mrows) {
                size_t rb = (size_t)grow * 256 + colbase + wc * 64 + (lane & 15);
#pragma unroll
                for (int fc = 0; fc < 4; ++fc) {
                    float v = acc[fr][fc][i] + bcol[fc];
                    Yp[rb + fc * 16] = f2bf(v);
                    if (STATS) { ps[fc] += v; pq[fc] += v * v; }
                }
            }
        }
    }
    if (STATS) {
#pragma unroll
        for (int fc = 0; fc < 4; ++fc) {
            float s = ps[fc], q2 = pq[fc];
            s += __shfl_xor(s, 16); s += __shfl_xor(s, 32);
            q2 += __shfl_xor(q2, 16); q2 += __shfl_xor(q2, 32);
            if (lane < 16) {
                int col = colbase + wc * 64 + fc * 16 + lane;
                atomicAdd(&ssum[c * 256 + col], s);
                atomicAdd(&ssq[c * 256 + col], q2);
            }
        }
    }
}

// ---------------- FUSED sage: Y = gelu(chattn([Agg|H] @ Wfold^T + biasF) + H) ----------------
// 64 rows x 256 cols tile, K=512 in 16 steps of 32, 512 threads / 8 waves.
// Double-buffered staging, 20KB/buf -> LDS 40KB -> 4 blocks/CU = 32 waves/CU.
template <int SMODE>   // 1: sum+sumsq, 2: sum only
__global__ __launch_bounds__(512) void msage_k(
    const u16* __restrict__ A1,                 // Agg slabs
    const u16* __restrict__ A2,                 // H slabs (also residual, in-place out)
    const u16* __restrict__ Wt, size_t sW,      // folded weights [256][512] per config
    const float* __restrict__ biasF,            // [nc][256]
    const u16* __restrict__ W1p, const float* __restrict__ b1,
    const u16* __restrict__ W2p, const float* __restrict__ b2,
    u16* __restrict__ Yout, int Mrows,
    float* __restrict__ ssum, float* __restrict__ ssq)
{
    __shared__ __align__(16) char SM[40960];
    // buf b: A at b*20480 (4096 B, 64x32), B at b*20480+4096 (16384 B, 256x32)
    u16*   xbf = (u16*)SM;                      // 64x264  (epilogue, aliases bufs)
    u16*   tbf = (u16*)(SM + 33792);            // 64x40   (epilogue)
    float* red = (float*)SM;                    // stats reduce (aliases dead xbf)

    const int tid = threadIdx.x;
    const int lane = tid & 63, w = tid >> 6;     // wave 0..7 (col-32 slice)
    const int cl = lane & 15, kq = lane >> 4;

    // XCD-aware bijective remap over (by, c)
    int nwg = gridDim.x * gridDim.y;
    int orig = blockIdx.x + gridDim.x * blockIdx.y;
    int q = nwg >> 3, r = nwg & 7;
    int xcd = orig & 7, idx = orig >> 3;
    int swz = (xcd < r ? xcd * (q + 1) : r * (q + 1) + (xcd - r) * q) + idx;
    const int by = swz % gridDim.x;
    const int c  = swz / gridDim.x;
    const int rowbase = by * 64;

    const u16* A1p = A1 + (size_t)c * SZ_;
    const u16* A2p = A2 + (size_t)c * SZ_;
    const u16* Wp  = Wt + (size_t)c * sW;

    f32x4 acc[4][2];
#pragma unroll
    for (int i = 0; i < 4; ++i)
#pragma unroll
        for (int j = 0; j < 2; ++j) acc[i][j] = (f32x4)0.f;

    // K-step = 32: A tile 64x32 (256 16B units), B tile 256x32 (1024 units)
    auto stage = [&](int buf, int k0) {
        const u16* asrc = (k0 < 256) ? A1p : A2p;
        const int ak = (k0 < 256) ? k0 : (k0 - 256);
        u16* Ab = (u16*)(SM + buf * 20480);
        u16* Bb = (u16*)(SM + buf * 20480 + 4096);
        // A: 256 units, threads 0..255 (waves 0..3), 1/thread
        if (tid < 256) {
            const int row = tid >> 2, chunk = tid & 3;
            const int sc2 = chunk ^ (row & 3);
            int garow = rowbase + row;
            if (garow >= Mrows) garow = Mrows - 1;
            __builtin_amdgcn_global_load_lds(
                (glb_uint*)(asrc + (size_t)garow * 256 + ak + sc2 * 8),
                (lds_uint*)(Ab + tid * 8), 16, 0, 0);
        }
        // B: 1024 units, 2/thread
#pragma unroll
        for (int jj = 0; jj < 2; ++jj) {
            const int u = tid + jj * 512;
            const int wcol = u >> 2, chunk = u & 3;
            const int sc2 = chunk ^ (wcol & 3);
            __builtin_amdgcn_global_load_lds(
                (glb_uint*)(Wp + (size_t)wcol * 512 + k0 + sc2 * 8),
                (lds_uint*)(Bb + u * 8), 16, 0, 0);
        }
    };

    // ---- 2-phase pipelined K loop: Ktot = 512, 16 steps of 32 ----
    stage(0, 0);
    __syncthreads();                 // drain prologue stage (implicit vmcnt(0))
    int cur = 0;
    for (int t = 0; t < 16; ++t) {
        if (t < 15) stage(cur ^ 1, (t + 1) * 32);   // overlap with MFMA below
        const u16* Asm = (const u16*)(SM + cur * 20480);
        const u16* Bsm = (const u16*)(SM + cur * 20480 + 4096);
        {
            s16x8 aF[4], bF[2];
            const int kk = kq * 8;
#pragma unroll
            for (int f = 0; f < 4; ++f) {
                const int ar = f * 16 + cl;
                aF[f] = *(const s16x8*)&Asm[(ar * 32 + kk) ^ ((ar & 3) << 3)];
            }
#pragma unroll
            for (int fc = 0; fc < 2; ++fc) {
                const int bc = w * 32 + fc * 16 + cl;
                bF[fc] = *(const s16x8*)&Bsm[(bc * 32 + kk) ^ ((bc & 3) << 3)];
            }
#pragma unroll
            for (int fr = 0; fr < 4; ++fr)
#pragma unroll
                for (int fc = 0; fc < 2; ++fc)
                    acc[fr][fc] = __builtin_amdgcn_mfma_f32_16x16x32_bf16(
                        aF[fr], bF[fc], acc[fr][fc], 0, 0, 0);
        }
        __syncthreads();             // drains vmcnt(0): next buf ready, cur reads done
        cur ^= 1;
    }

    float bcol[2];
#pragma unroll
    for (int fc = 0; fc < 2; ++fc)
        bcol[fc] = biasF[c * 256 + w * 32 + fc * 16 + cl];

    // ---- attention epilogue ----
#pragma unroll
    for (int fr = 0; fr < 4; ++fr)
#pragma unroll
        for (int i = 0; i < 4; ++i) {
            const int rloc = fr * 16 + kq * 4 + i;
#pragma unroll
            for (int fc = 0; fc < 2; ++fc)
                xbf[rloc * 264 + w * 32 + fc * 16 + cl] =
                    f2bf(acc[fr][fc][i] + bcol[fc]);
        }
    __syncthreads();
    // t = relu(x@W1 + b1): wave = (rb = w>>1 row-block, ch = w&1 col-half), K=256
    {
        const int rb = w >> 1, ch = w & 1;
        f32x4 at = (f32x4)0.f;
#pragma unroll
        for (int s = 0; s < 8; ++s) {
            s16x8 aF = *(const s16x8*)&xbf[(rb * 16 + cl) * 264 + s * 32 + kq * 8];
            s16x8 bF = *(const s16x8*)&W1p[((s * 2 + ch) * 64 + lane) * 8];
            at = __builtin_amdgcn_mfma_f32_16x16x32_bf16(aF, bF, at, 0, 0, 0);
        }
        const float b1v = b1[ch * 16 + cl];
#pragma unroll
        for (int i = 0; i < 4; ++i)
            tbf[(rb * 16 + kq * 4 + i) * 40 + ch * 16 + cl] =
                f2bf(fmaxf(at[i] + b1v, 0.f));
    }
    __syncthreads();
    // y' = sigmoid(t@W2 + b2) * x  -> back into xbf (wave = col-32 slice, 2 col frags)
    {
        s16x8 aF[4];
#pragma unroll
        for (int rg = 0; rg < 4; ++rg)
            aF[rg] = *(const s16x8*)&tbf[(rg * 16 + cl) * 40 + kq * 8];
#pragma unroll
        for (int q2 = 0; q2 < 2; ++q2) {
            const int cf = w * 2 + q2;            // 0..15
            const int colb = cf * 16;
            s16x8 bF = *(const s16x8*)&W2p[(cf * 64 + lane) * 8];
            const float b2v = b2[colb + cl];
#pragma unroll
            for (int rg = 0; rg < 4; ++rg) {
                f32x4 a2 = __builtin_amdgcn_mfma_f32_16x16x32_bf16(
                    aF[rg], bF, (f32x4)0.f, 0, 0, 0);
#pragma unroll
                for (int i = 0; i < 4; ++i) {
                    const int ea = (rg * 16 + kq * 4 + i) * 264 + colb + cl;
                    float s = a2[i] + b2v;
                    float sig = 1.f / (1.f + __expf(-s));
                    xbf[ea] = f2bf(sig * bf2f(xbf[ea]));
                }
            }
        }
    }
    __syncthreads();
    // gelu(y' + res), coalesced store + stats (32 elements/thread)
    float ps[8] = {0, 0, 0, 0, 0, 0, 0, 0}, pq[8] = {0, 0, 0, 0, 0, 0, 0, 0};
#pragma unroll
    for (int it = 0; it < 4; ++it) {
        const int e = tid + it * 512;
        const int row = e >> 5, cb = (e & 31) * 8;
        const int grow = rowbase + row;
        if (grow < Mrows) {
            us8v xv = *(const us8v*)&xbf[row * 264 + cb];
            us8v rv = *(const us8v*)&Yout[((size_t)c * N_ + grow) * 256 + cb];
            us8v ov;
#pragma unroll
            for (int j = 0; j < 8; ++j) {
                float v = gelu_f(bf2f(xv[j]) + bf2f(rv[j]));
                ov[j] = f2bf(v);
                ps[j] += v;
                if (SMODE == 1) pq[j] += v * v;
            }
            *(us8v*)&Yout[((size_t)c * N_ + grow) * 256 + cb] = ov;
        }
    }
    __syncthreads();                 // xbf dead -> red may alias it
#pragma unroll
    for (int j = 0; j < 8; ++j)
        red[((tid >> 5) * 32 + (tid & 31)) * 8 + j] = ps[j];
    __syncthreads();
    if (tid < 256) {
        const int cb2 = tid >> 3, j2 = tid & 7;
        float s = 0.f;
#pragma unroll
        for (int r16 = 0; r16 < 16; ++r16) s += red[(r16 * 32 + cb2) * 8 + j2];
        atomicAdd(&ssum[c * 256 + cb2 * 8 + j2], s);
    }
    if (SMODE == 1) {
        __syncthreads();
#pragma unroll
        for (int j = 0; j < 8; ++j)
            red[((tid >> 5) * 32 + (tid & 31)) * 8 + j] = pq[j];
        __syncthreads();
        if (tid < 256) {
            const int cb2 = tid >> 3, j2 = tid & 7;
            float s = 0.f;
#pragma unroll
            for (int r16 = 0; r16 < 16; ++r16) s += red[(r16 * 32 + cb2) * 8 + j2];
            atomicAdd(&ssq[c * 256 + cb2 * 8 + j2], s);
        }
    }
}

// ---------------- fp32 tiled GEMM (one-time base GEMM) ----------------
__global__ __launch_bounds__(256) void gemm_k(const float* __restrict__ A1, int lda1,
                                              const float* __restrict__ W1, int K1,
                                              const float* __restrict__ bias,
                                              float* __restrict__ Y, int Mrows) {
    __shared__ float As[16][132];
    __shared__ float Bs[16][132];
    float acc[8][8];
#pragma unroll
    for (int i = 0; i < 8; ++i)
#pragma unroll
        for (int j = 0; j < 8; ++j) acc[i][j] = 0.f;

    const int tid = threadIdx.x;
    const int tr = tid >> 4, tc = tid & 15;
    const int rowbase = blockIdx.y * 128, colbase = blockIdx.x * 128;

    for (int k0 = 0; k0 < K1; k0 += 16) {
#pragma unroll
        for (int ii = 0; ii < 2; ++ii) {
            int i = tid + ii * 256;
            int rr = i >> 2, qq = i & 3;
            int grow = rowbase + rr;
            float4 vv = make_float4(0.f, 0.f, 0.f, 0.f);
            if (grow < Mrows) vv = *(const float4*)&A1[(size_t)grow * lda1 + k0 + qq * 4];
            As[qq * 4 + 0][rr] = vv.x;
            As[qq * 4 + 1][rr] = vv.y;
            As[qq * 4 + 2][rr] = vv.z;
            As[qq * 4 + 3][rr] = vv.w;
        }
#pragma unroll
        for (int ii = 0; ii < 2; ++ii) {
            int i = tid + ii * 256;
            int rr = i >> 5, qq = i & 31;
            float4 vv = *(const float4*)&W1[(size_t)(k0 + rr) * 256 + colbase + qq * 4];
            *(float4*)&Bs[rr][qq * 4] = vv;
        }
        __syncthreads();
#pragma unroll
        for (int kk = 0; kk < 16; ++kk) {
            float a[8], b[8];
            *(float4*)&a[0] = *(const float4*)&As[kk][tr * 4];
            *(float4*)&a[4] = *(const float4*)&As[kk][64 + tr * 4];
            *(float4*)&b[0] = *(const float4*)&Bs[kk][tc * 4];
            *(float4*)&b[4] = *(const float4*)&Bs[kk][64 + tc * 4];
#pragma unroll
            for (int i = 0; i < 8; ++i)
#pragma unroll
                for (int j = 0; j < 8; ++j)
                    acc[i][j] = fmaf(a[i], b[j], acc[i][j]);
        }
        __syncthreads();
    }

    float4 blo = *(const float4*)&bias[colbase + tc * 4];
    float4 bhi = *(const float4*)&bias[colbase + 64 + tc * 4];
    float bb[8] = {blo.x, blo.y, blo.z, blo.w, bhi.x, bhi.y, bhi.z, bhi.w};
#pragma unroll
    for (int i = 0; i < 8; ++i)
#pragma unroll
        for (int j = 0; j < 8; ++j) acc[i][j] += bb[j];

#pragma unroll
    for (int i = 0; i < 8; ++i) {
        int lrow = (i < 4) ? (tr * 4 + i) : (64 + tr * 4 + (i - 4));
        int grow = rowbase + lrow;
        if (grow < Mrows) {
            *(float4*)&Y[(size_t)grow * 256 + colbase + tc * 4] =
                make_float4(acc[i][0], acc[i][1], acc[i][2], acc[i][3]);
            *(float4*)&Y[(size_t)grow * 256 + colbase + 64 + tc * 4] =
                make_float4(acc[i][4], acc[i][5], acc[i][6], acc[i][7]);
        }
    }
}

// ---------------- per-row epilogue with MFMA channel-attention (512 thr, 8 waves) ----------------
// norm stats computed inline from nssum/nssq (finstat removed)
template <int NORM, int RES, int SMODE>
__global__ __launch_bounds__(512) void apply_k(const u16* __restrict__ Yin,
                                               u16* __restrict__ Hout,
                                               const u16* __restrict__ Hsc,
                                               const u16* __restrict__ W1p,
                                               const float* __restrict__ b1,
                                               const u16* __restrict__ W2p,
                                               const float* __restrict__ b2,
                                               const float* __restrict__ nssum,
                                               const float* __restrict__ nssq,
                                               float* __restrict__ ssum,
                                               float* __restrict__ ssq) {
    __shared__ u16 vbf[16 * 264];
    __shared__ u16 scs[(RES ? 16 : 1) * 264];
    __shared__ float tpart[8 * 528];
    __shared__ u16 tbf[16 * 40];
    __shared__ float srs[NORM ? 256 : 1], smrs[NORM ? 256 : 1];
    const int c = blockIdx.z, n0 = blockIdx.x * 16, tid = threadIdx.x;
    const int lane = tid & 63, wid = tid >> 6;   // wid 0..7
    const size_t rowbase = ((size_t)c * N_ + n0) * 256;

    if (NORM && tid < 256) {
        float m = nssum[c * 256 + tid] * (1.0f / (float)N_);
        float v = nssq[c * 256 + tid] * (1.0f / (float)N_) - m * m;
        float r = rsqrtf(v + EPS_);
        srs[tid] = r;
        smrs[tid] = m * r;
    }
    {
        const int row = tid >> 5, cb = (tid & 31) * 8;
        us8v x = *(const us8v*)&Yin[rowbase + row * 256 + cb];
        us8v r;
        if (RES) r = *(const us8v*)&Hsc[rowbase + row * 256 + cb];
        if (NORM) {
            __syncthreads();
            us8v y;
#pragma unroll
            for (int j = 0; j < 8; ++j)
                y[j] = f2bf(fmaf(bf2f(x[j]), srs[cb + j], -smrs[cb + j]));
            *(us8v*)&vbf[row * 264 + cb] = y;
        } else {
            *(us8v*)&vbf[row * 264 + cb] = x;
        }
        if (RES) *(us8v*)&scs[row * 264 + cb] = r;
    }
    __syncthreads();

    {
        const int arow = lane & 15, kq = lane >> 4;
        const int k = wid * 32 + kq * 8;
        s16x8 aF = *(const s16x8*)&vbf[arow * 264 + k];
        s16x8 bF0 = *(const s16x8*)&W1p[((wid * 2 + 0) * 64 + lane) * 8];
        s16x8 bF1 = *(const s16x8*)&W1p[((wid * 2 + 1) * 64 + lane) * 8];
        f32x4 at0 = __builtin_amdgcn_mfma_f32_16x16x32_bf16(aF, bF0, (f32x4)0.f, 0, 0, 0);
        f32x4 at1 = __builtin_amdgcn_mfma_f32_16x16x32_bf16(aF, bF1, (f32x4)0.f, 0, 0, 0);
#pragma unroll
        for (int i = 0; i < 4; ++i) {
            tpart[wid * 528 + (kq * 4 + i) * 33 + (lane & 15)] = at0[i];
            tpart[wid * 528 + (kq * 4 + i) * 33 + 16 + (lane & 15)] = at1[i];
        }
    }
    __syncthreads();

    {
        const int nr = tid >> 5, col = tid & 31;
        float s = b1[col];
#pragma unroll
        for (int w8 = 0; w8 < 8; ++w8)
            s += tpart[w8 * 528 + nr * 33 + col];
        tbf[nr * 40 + col] = f2bf(fmaxf(s, 0.f));
    }
    __syncthreads();

    {
        const int cl = lane & 15, kq = lane >> 4;
        s16x8 aF = *(const s16x8*)&tbf[cl * 40 + kq * 8];
        float ps[2] = {0, 0}, pq[2] = {0, 0};
#pragma unroll
        for (int q = 0; q < 2; ++q) {
            const int colb = (wid * 2 + q) * 16;
            s16x8 bF = *(const s16x8*)&W2p[((wid * 2 + q) * 64 + lane) * 8];
            f32x4 acc = __builtin_amdgcn_mfma_f32_16x16x32_bf16(aF, bF, (f32x4)0.f, 0, 0, 0);
            const float b2v = b2[colb + cl];
#pragma unroll
            for (int i = 0; i < 4; ++i) {
                const int row = kq * 4 + i;
                const int ea = row * 264 + colb + cl;
                float s = acc[i] + b2v;
                float sig = 1.0f / (1.0f + __expf(-s));
                float val = sig * bf2f(vbf[ea]);
                if (RES) val += bf2f(scs[ea]);
                val = gelu_f(val);
                vbf[ea] = f2bf(val);
                if (SMODE) { ps[q] += val; if (SMODE == 1) pq[q] += val * val; }
            }
        }
        if (SMODE) {
#pragma unroll
            for (int q = 0; q < 2; ++q) {
                float s = ps[q];
                s += __shfl_xor(s, 16); s += __shfl_xor(s, 32);
                if (SMODE == 1) {
                    float q2 = pq[q];
                    q2 += __shfl_xor(q2, 16); q2 += __shfl_xor(q2, 32);
                    if (lane < 16) atomicAdd(&ssq[c * 256 + (wid * 2 + q) * 16 + lane], q2);
                }
                if (lane < 16) atomicAdd(&ssum[c * 256 + (wid * 2 + q) * 16 + lane], s);
            }
        }
    }
    __syncthreads();

    {
        const int row = tid >> 5, cb = (tid & 31) * 8;
        us8v h = *(const us8v*)&vbf[row * 264 + cb];
        *(us8v*)&Hout[rowbase + row * 256 + cb] = h;
    }
}

// ---------------- classifier ----------------
__global__ __launch_bounds__(256) void cls_k(const float* __restrict__ pooled_sum,
                                             const float* __restrict__ clsW,
                                             const float* __restrict__ clsb,
                                             float* __restrict__ out) {
    __shared__ float red[256];
    int c = blockIdx.x, d = threadIdx.x;
    red[d] = pooled_sum[c * 256 + d] * (1.0f / (float)N_) * clsW[d];
    __syncthreads();
    for (int s = 128; s > 0; s >>= 1) {
        if (d < s) red[d] += red[d + s];
        __syncthreads();
    }
    if (d == 0) out[c] = red[0] + clsb[0];
}

// ---------------- host launch ----------------
static inline size_t alup(size_t x) { return (x + 255) & ~(size_t)255; }

extern "C" void kernel_launch(void* const* d_in, const int* in_sizes, int n_in,
                              void* d_out, int out_size, void* d_ws, size_t ws_size,
                              hipStream_t stream) {
    const int*   xcfg   = (const int*)d_in[0];
    const float* xfeat  = (const float*)d_in[1];
    const int*   xlay   = (const int*)d_in[2];
    const int*   xop    = (const int*)d_in[3];
    const int*   ei     = (const int*)d_in[4];
    const int*   ncid   = (const int*)d_in[5];
    const float* embO   = (const float*)d_in[6];
    const float* embL   = (const float*)d_in[7];
    const float* lin1W  = (const float*)d_in[8];
    const float* lin1b  = (const float*)d_in[9];
    const float* ca1W1  = (const float*)d_in[10];
    const float* ca1b1  = (const float*)d_in[11];
    const float* ca1W2  = (const float*)d_in[12];
    const float* ca1b2  = (const float*)d_in[13];
    const float* lin2W  = (const float*)d_in[14];
    const float* lin2b  = (const float*)d_in[15];
    const float* ca2W1  = (const float*)d_in[16];
    const float* ca2b1  = (const float*)d_in[17];
    const float* ca2W2  = (const float*)d_in[18];
    const float* ca2b2  = (const float*)d_in[19];
    const float* sageWl = (const float*)d_in[20];
    const float* sagebl = (const float*)d_in[21];
    const float* sageWr = (const float*)d_in[22];
    const float* scaW1  = (const float*)d_in[23];
    const float* scab1  = (const float*)d_in[24];
    const float* scaW2  = (const float*)d_in[25];
    const float* scab2  = (const float*)d_in[26];
    const float* clsW   = (const float*)d_in[27];
    const float* clsb   = (const float*)d_in[28];
    float* out = (float*)d_out;

    // ---- workspace carve-up ----
    char* w = (char*)d_ws;
    size_t o = 0;
    auto take = [&](size_t bytes) { char* p = w + o; o = alup(o + bytes); return p; };
    float* base    = (float*)take((size_t)N_ * 256 * 4);
    float* feat162 = (float*)take((size_t)N_ * 176 * 4);
    float* W162    = (float*)take((size_t)176 * 256 * 4);
    float* T       = (float*)take((size_t)18 * 8 * 256 * 4);
    float* csum    = (float*)take((size_t)256 * 4);
    float* stats   = (float*)take((size_t)6 * 8192 * 4);
    float* invcnt  = (float*)take((size_t)N_ * 4);
    int*   cnt     = (int*)take((size_t)N_ * 4);
    int*   off     = (int*)take((size_t)(N_ + 1) * 4);
    int*   cursor  = (int*)take((size_t)N_ * 4);
    int*   csr     = (int*)take((size_t)E_ * 4);
    int*   cfgpos  = (int*)take((size_t)N_ * 4);
    u16*   Wt2     = (u16*)take((size_t)256 * 256 * 2);
    u16*   Wfold   = (u16*)take((size_t)C_ * 256 * 512 * 2);   // 4 MB
    float* biasF   = (float*)take((size_t)C_ * 256 * 4);
    u16*   CAW1    = (u16*)take((size_t)5 * 8192 * 2);         // packed frag order
    u16*   CAW2    = (u16*)take((size_t)5 * 8192 * 2);

    const size_t slab = (size_t)SZ_ * 2;                       // bf16: 5.12 MB
    size_t avail = (ws_size > o) ? (ws_size - o) : 0;
    int Cc = (int)(avail / (3 * slab + 768));
    if (Cc > C_) Cc = C_;
    if (Cc < 1) Cc = 1;
    u16* BufH = (u16*)take((size_t)Cc * slab);
    u16* BufY = (u16*)take((size_t)Cc * slab);
    u16* BufA = (u16*)take((size_t)Cc * slab);
    (void)in_sizes; (void)n_in; (void)out_size;

    auto S = [&](int s) { return stats + (size_t)s * 8192; };
    auto Q = [&](int s) { return stats + (size_t)s * 8192 + 4096; };

    hipMemsetAsync(stats, 0, 6 * 8192 * 4, stream);
    hipMemsetAsync(cnt, 0, N_ * 4, stream);
    hipMemsetAsync(cfgpos, 0xFF, N_ * 4, stream);

    // shared prep
    tbl_k<<<144, 256, 0, stream>>>(embL, lin1W, T);
    csum_k<<<1, 256, 0, stream>>>(T, csum);
    feat_k<<<N_, 192, 0, stream>>>(xfeat, xlay, xop, embL, embO, feat162);
    wpack_k<<<176, 256, 0, stream>>>(lin1W, W162);
    wt2_k<<<256, 256, 0, stream>>>(lin2W, Wt2);
    packw1_k<<<32, 256, 0, stream>>>(ca1W1, CAW1 + 0 * 8192);
    packw1_k<<<32, 256, 0, stream>>>(ca2W1, CAW1 + 1 * 8192);
    packw1_k<<<32, 256, 0, stream>>>(scaW1 + 0 * 8192, CAW1 + 2 * 8192);
    packw1_k<<<32, 256, 0, stream>>>(scaW1 + 1 * 8192, CAW1 + 3 * 8192);
    packw1_k<<<32, 256, 0, stream>>>(scaW1 + 2 * 8192, CAW1 + 4 * 8192);
    packw2_k<<<32, 256, 0, stream>>>(ca1W2, CAW2 + 0 * 8192);
    packw2_k<<<32, 256, 0, stream>>>(ca2W2, CAW2 + 1 * 8192);
    packw2_k<<<32, 256, 0, stream>>>(scaW2 + 0 * 8192, CAW2 + 2 * 8192);
    packw2_k<<<32, 256, 0, stream>>>(scaW2 + 1 * 8192, CAW2 + 3 * 8192);
    packw2_k<<<32, 256, 0, stream>>>(scaW2 + 2 * 8192, CAW2 + 4 * 8192);
    cfgpos_k<<<(NC_ + 255) / 256, 256, 0, stream>>>(ncid, cfgpos);
    hist_k<<<(E_ + 255) / 256, 256, 0, stream>>>(ei, cnt);
    scan_k<<<1, 1024, 0, stream>>>(cnt, off, cursor, invcnt);
    fill_k<<<(E_ + 255) / 256, 256, 0, stream>>>(ei, cursor, csr);

    // base = feat162 @ W162 + lin1_b (fp32, one-time)
    gemm_k<<<dim3(2, 79, 1), 256, 0, stream>>>(feat162, 176, W162, 176, lin1b, base, N_);

    // ---- per-config-chunk pipeline ----
    for (int c0 = 0; c0 < C_; c0 += Cc) {
        const int nc = (C_ - c0 < Cc) ? (C_ - c0) : Cc;
        const int co = c0 * 256;

        lin1_cfg_k<<<dim3(NC_ / 16, 1, nc), 256, 0, stream>>>(
            base, T, ncid, xcfg + (size_t)c0 * NC_ * 18, BufH, S(0) + co, Q(0) + co);
        lin1_unc_k<<<625, 256, 0, stream>>>(
            base, csum, cfgpos, nc, BufH, S(0) + co, Q(0) + co);

        apply_k<1, 0, 0><<<dim3(625, 1, nc), 512, 0, stream>>>(
            BufH, BufH, nullptr, CAW1 + 0 * 8192, ca1b1, CAW2 + 0 * 8192, ca1b2,
            S(0) + co, Q(0) + co, nullptr, nullptr);

        mgemm_k<1><<<dim3(2, 79, nc), 256, 0, stream>>>(
            BufH, SZ_, nullptr, 0, Wt2, 0, 256, 256,
            lin2b, 0, BufY, SZ_, N_, S(1) + co, Q(1) + co);

        apply_k<1, 0, 1><<<dim3(625, 1, nc), 512, 0, stream>>>(
            BufY, BufY, nullptr, CAW1 + 1 * 8192, ca2b1, CAW2 + 1 * 8192, ca2b2,
            S(1) + co, Q(1) + co, S(2) + co, Q(2) + co);

        for (int i = 0; i < 3; ++i) {
            const int set = 2 + i;
            foldw_k<<<dim3(256, nc), 256, 0, stream>>>(
                sageWl + (size_t)i * 65536, sageWr + (size_t)i * 65536, sagebl + i * 256,
                S(set) + co, Q(set) + co,
                Wfold + (size_t)c0 * 256 * 512, biasF + co);
            agg_k<<<nc * 2500, 256, 0, stream>>>(BufY, off, csr, invcnt,
                                                 S(set) + co, BufA);
            if (i < 2) {
                msage_k<1><<<dim3(157, nc), 512, 0, stream>>>(
                    BufA, BufY, Wfold + (size_t)c0 * 256 * 512, 256 * 512, biasF + co,
                    CAW1 + (2 + i) * 8192, scab1 + i * 32,
                    CAW2 + (2 + i) * 8192, scab2 + i * 256,
                    BufY, N_, S(3 + i) + co, Q(3 + i) + co);
            } else {
                msage_k<2><<<dim3(157, nc), 512, 0, stream>>>(
                    BufA, BufY, Wfold + (size_t)c0 * 256 * 512, 256 * 512, biasF + co,
                    CAW1 + (2 + i) * 8192, scab1 + i * 32,
                    CAW2 + (2 + i) * 8192, scab2 + i * 256,
                    BufY, N_, S(5) + co, nullptr);
            }
        }
    }

    cls_k<<<16, 256, 0, stream>>>(S(5), clsW, clsb, out);
}